// Round 1
// 382.013 us; speedup vs baseline: 1.0337x; 1.0337x over previous
//
#include <hip/hip_runtime.h>
#include <hip/hip_bf16.h>

// HybridSelfAttention: out = softmax((xWq)(xWk)^T / sqrt(d)) (xWv)
// B=4, S=2048, D=1024, fp32 in/out.
//
// Precision: f16 hi/lo split + 3-product MFMA for xWq, xWk, QK^T (softmax is
// near-one-hot; S must be ~fp32-accurate). Plain f16 MFMA for V^T and PV.
//
// R1: LDS chunk swizzle -> bank conflicts 8.4M -> 0.
// R2: dispatch fusion (QK proj fused, V^T direct GEMM, weight prep merged).
// R3: MFMA 32x32x16.
// R5: swizzle fix f(r)=((r>>1)+(r>>4))&3 -> conflicts 0; dur unchanged ->
//   latency-stall diagnosis (MfmaUtil 35 + VALU 11, HBM 21% -- nothing bound).
// R6/R7: register-staging transport -> compiler spilled -> dead end.
// R8: double-buffered LDS, one barrier per K-iter -> 888 TF effective; this is
//   the measured ceiling of the 1-barrier-per-K-step structure (MfmaUtil 40).
// R9: port the two NPROD=3 GEMMs (QK-proj, S) to the 256^2 8-wave phase-split
//   schedule (T3+T4+T5): 512 thr (8 waves, 2x4), BK=32, 4 tiles (A0,B0,A1,B1)
//   double-buffered = 128 KiB LDS, 3 phases/K-step (one per product), each
//   phase = {ds_read frags; raw s_barrier; lgkmcnt(0)+sched_barrier; setprio(1)
//   16 MFMA setprio(0); s_barrier}. All 8 stage calls front-loaded in P0; the
//   only vmcnt wait is at P2 (~2.5 phases after issue -> no fresh-load stall).
//   V^T and PV stay on the 128^2 kernel (256^2 would leave half the CUs idle).

typedef _Float16 half8 __attribute__((ext_vector_type(8)));
typedef _Float16 half4v __attribute__((ext_vector_type(4)));
typedef float f32x16 __attribute__((ext_vector_type(16)));

#define GLOBAL_AS __attribute__((address_space(1)))
#define LDS_AS __attribute__((address_space(3)))

__device__ __forceinline__ void gll16(const _Float16* g, _Float16* l) {
    // async global->LDS DMA, 16B per lane; LDS dest is wave-uniform base + lane*16
    __builtin_amdgcn_global_load_lds((GLOBAL_AS const void*)g, (LDS_AS void*)l, 16, 0, 0);
}

__device__ __forceinline__ void lgkm0_pin() {
    // rule 18: sched_barrier(0) right after an inline-asm lgkmcnt wait, else
    // hipcc can hoist register-only MFMA above the wait.
    asm volatile("s_waitcnt lgkmcnt(0)" ::: "memory");
    __builtin_amdgcn_sched_barrier(0);
}

template <int N>
__device__ __forceinline__ void vmwait() {
    if constexpr (N == 0) asm volatile("s_waitcnt vmcnt(0)" ::: "memory");
    else if constexpr (N == 4) asm volatile("s_waitcnt vmcnt(4)" ::: "memory");
    else asm volatile("s_waitcnt vmcnt(8)" ::: "memory");
}

// ---------------------------------------------------------------------------
// OLD 128x128 kernel (R8 structure) -- kept for the NPROD=1 ops (V^T, PV),
// whose grids would under-fill the chip at 256^2 tiles.
// ---------------------------------------------------------------------------
template <int NPROD, int OUTMODE>
__global__ __launch_bounds__(256) void gemm_nt(
    const _Float16* __restrict__ A0, const _Float16* __restrict__ A1,
    const _Float16* __restrict__ B0, const _Float16* __restrict__ B1,
    float* __restrict__ Cf, _Float16* __restrict__ C0, _Float16* __restrict__ C1,
    int lda, int ldb, int ldc, int K,
    long sA, long sB, long sC, float scale, float scale2) {
    constexpr int NTILES = (NPROD == 3) ? 4 : 2;
    constexpr int BUFH = NTILES * 4096;  // halves per buffer set
    __shared__ alignas(16) _Float16 smem[2 * BUFH];  // double-buffered tile sets

    const int tid = threadIdx.x;
    const int wave = tid >> 6, lane = tid & 63;
    const int wm = (wave >> 1) * 64, wn = (wave & 1) * 64;
    const int q2 = lane >> 5, r32 = lane & 31;

    const long zA = (long)blockIdx.z * sA;
    const long zB = (long)blockIdx.z * sB;
    const long zC = (long)blockIdx.z * sC;

    const float sc = (blockIdx.y * 2 < gridDim.y) ? scale : scale2;

    const int trow = tid >> 2;
    const int tcol = (((tid & 3) - ((tid >> 3) & 3) - ((tid >> 6) & 3)) & 3) * 8;
    const _Float16* gA0 = A0 + zA + (long)(blockIdx.x * 128 + trow) * lda + tcol;
    const _Float16* gB0 = B0 + zB + (long)(blockIdx.y * 128 + trow) * ldb + tcol;
    const _Float16* gA1 = (NPROD == 3) ? (A1 + zA + (long)(blockIdx.x * 128 + trow) * lda + tcol) : nullptr;
    const _Float16* gB1 = (NPROD == 3) ? (B1 + zB + (long)(blockIdx.y * 128 + trow) * ldb + tcol) : nullptr;

    f32x16 acc[2][2];
#pragma unroll
    for (int i = 0; i < 2; ++i)
#pragma unroll
        for (int j = 0; j < 2; ++j)
#pragma unroll
            for (int r = 0; r < 16; ++r) acc[i][j][r] = 0.f;

    const int ldsoff = tid * 8;
    const int fbase = q2 + (r32 >> 1) + (r32 >> 4);

    {
        _Float16* s = smem;
        gll16(gA0, s + ldsoff);
        gll16(gA0 + 64 * lda, s + ldsoff + 2048);
        gll16(gB0, s + 4096 + ldsoff);
        gll16(gB0 + 64 * ldb, s + 4096 + ldsoff + 2048);
        if (NPROD == 3) {
            gll16(gA1, s + 8192 + ldsoff);
            gll16(gA1 + 64 * lda, s + 8192 + ldsoff + 2048);
            gll16(gB1, s + 12288 + ldsoff);
            gll16(gB1 + 64 * ldb, s + 12288 + ldsoff + 2048);
        }
        gA0 += 32; gB0 += 32;
        if (NPROD == 3) { gA1 += 32; gB1 += 32; }
    }

    int buf = 0;
    for (int k0 = 0; k0 < K; k0 += 32) {
        __syncthreads();

        if (k0 + 32 < K) {
            _Float16* s = smem + (buf ^ 1) * BUFH;
            gll16(gA0, s + ldsoff);
            gll16(gA0 + 64 * lda, s + ldsoff + 2048);
            gll16(gB0, s + 4096 + ldsoff);
            gll16(gB0 + 64 * ldb, s + 4096 + ldsoff + 2048);
            if (NPROD == 3) {
                gll16(gA1, s + 8192 + ldsoff);
                gll16(gA1 + 64 * lda, s + 8192 + ldsoff + 2048);
                gll16(gB1, s + 12288 + ldsoff);
                gll16(gB1 + 64 * ldb, s + 12288 + ldsoff + 2048);
            }
            gA0 += 32; gB0 += 32;
            if (NPROD == 3) { gA1 += 32; gB1 += 32; }
        }

        _Float16* sA0 = smem + buf * BUFH;
        _Float16* sB0 = sA0 + 4096;
        _Float16* sA1 = (NPROD == 3) ? sA0 + 8192 : sA0;
        _Float16* sB1 = (NPROD == 3) ? sA0 + 12288 : sA0;
#pragma unroll
        for (int h = 0; h < 2; ++h) {
            half8 a0[2], b0[2], a1[2], b1[2];
#pragma unroll
            for (int i = 0; i < 2; ++i) {
                const int pp = ((fbase + 2 * i + 2 * h) & 3) * 8;
                a0[i] = *(const half8*)(sA0 + (wm + i * 32 + r32) * 32 + pp);
                b0[i] = *(const half8*)(sB0 + (wn + i * 32 + r32) * 32 + pp);
                if (NPROD == 3) {
                    a1[i] = *(const half8*)(sA1 + (wm + i * 32 + r32) * 32 + pp);
                    b1[i] = *(const half8*)(sB1 + (wn + i * 32 + r32) * 32 + pp);
                }
            }
#pragma unroll
            for (int i = 0; i < 2; ++i)
#pragma unroll
                for (int j = 0; j < 2; ++j) {
                    acc[i][j] = __builtin_amdgcn_mfma_f32_32x32x16_f16(a0[i], b0[j], acc[i][j], 0, 0, 0);
                    if (NPROD == 3) {
                        acc[i][j] = __builtin_amdgcn_mfma_f32_32x32x16_f16(a0[i], b1[j], acc[i][j], 0, 0, 0);
                        acc[i][j] = __builtin_amdgcn_mfma_f32_32x32x16_f16(a1[i], b0[j], acc[i][j], 0, 0, 0);
                    }
                }
        }
        buf ^= 1;
    }

    const int crow0 = blockIdx.x * 128 + wm + 4 * q2;
    const int ccol0 = blockIdx.y * 128 + wn + r32;
#pragma unroll
    for (int i = 0; i < 2; ++i)
#pragma unroll
        for (int j = 0; j < 2; ++j)
#pragma unroll
            for (int r = 0; r < 16; ++r) {
                int row = crow0 + i * 32 + (r & 3) + 8 * (r >> 2);
                long off = zC + (long)row * ldc + (ccol0 + j * 32);
                float v = acc[i][j][r] * sc;
                if (OUTMODE == 0) {
                    Cf[off] = v;
                } else if (OUTMODE == 2) {
                    C0[off] = (_Float16)v;
                } else {
                    _Float16 h = (_Float16)v;
                    C0[off] = h;
                    C1[off] = (_Float16)(v - (float)h);
                }
            }
}

// ---------------------------------------------------------------------------
// NEW: 256x256-tile, 8-wave, phase-split NT GEMM for the NPROD=3 products.
// C[M,N] = (A0+A1)(B0+B1)^T ~= A0B0 + A0B1 + A1B0  (A,B row-major, K inner)
// 512 thr = 8 waves (2 M x 4 N), per-wave 128x64 output (acc[4][2] f32x16).
// BK=32; LDS: 2 bufs x {A0,B0,A1,B1} x [256][32] f16 = 128 KiB.
// Per K-step: 3 phases (one product each, 16 MFMA). Each phase:
//   {ds_read this phase's frags; (P0: issue all 8 next-tile gll16);
//    s_barrier; lgkmcnt(0)+sched_barrier; setprio(1) MFMA x16 setprio(0);
//    (P2: vmcnt(0) -- next-tile loads are ~2.5 phases old); s_barrier}
// Chunk swizzle identical to the 128^2 kernel: f(row) reduces to the same
// fbase formula for wm in {0,128}, wn in {0,64,128,192}, and staging row+128
// (all extra terms == 0 mod 4).
// ---------------------------------------------------------------------------
__device__ __forceinline__ void ld_a(half8 (&d)[4][2], const _Float16* base,
                                     int wm, int r32, int fbase) {
#pragma unroll
    for (int i = 0; i < 4; ++i)
#pragma unroll
        for (int h = 0; h < 2; ++h)
            d[i][h] = *(const half8*)(base + (wm + 32 * i + r32) * 32 +
                                      ((fbase + 2 * i + 2 * h) & 3) * 8);
}

__device__ __forceinline__ void ld_b(half8 (&d)[2][2], const _Float16* base,
                                     int wn, int r32, int fbase) {
#pragma unroll
    for (int j = 0; j < 2; ++j)
#pragma unroll
        for (int h = 0; h < 2; ++h)
            d[j][h] = *(const half8*)(base + (wn + 32 * j + r32) * 32 +
                                      ((fbase + 2 * j + 2 * h) & 3) * 8);
}

__device__ __forceinline__ void mfma_blk(f32x16 (&acc)[4][2], const half8 (&a)[4][2],
                                         const half8 (&b)[2][2]) {
#pragma unroll
    for (int i = 0; i < 4; ++i)
#pragma unroll
        for (int j = 0; j < 2; ++j) {
            acc[i][j] = __builtin_amdgcn_mfma_f32_32x32x16_f16(a[i][0], b[j][0], acc[i][j], 0, 0, 0);
            acc[i][j] = __builtin_amdgcn_mfma_f32_32x32x16_f16(a[i][1], b[j][1], acc[i][j], 0, 0, 0);
        }
}

__device__ __forceinline__ void stage_tile(_Float16* dst, const _Float16* g, int ld,
                                           int ldsoff) {
    // [256][32] f16 tile = 2 gll16 groups of 128 rows (512 thr x 16B each)
    gll16(g, dst + ldsoff);
    gll16(g + (long)128 * ld, dst + 4096 + ldsoff);
}

template <int OUTMODE>
__global__ __launch_bounds__(512, 2) void gemm8p(
    const _Float16* __restrict__ A0, const _Float16* __restrict__ A1,
    const _Float16* __restrict__ B0, const _Float16* __restrict__ B1,
    float* __restrict__ Cf, _Float16* __restrict__ C0, _Float16* __restrict__ C1,
    int lda, int ldb, int ldc, int K,
    long sA, long sB, long sC, float scale, float scale2) {
    __shared__ alignas(16) _Float16 smem[65536];  // 128 KiB: 2 x {A0,B0,A1,B1}

    const int tid = threadIdx.x;
    const int wave = tid >> 6, lane = tid & 63;
    const int wm = (wave >> 2) * 128, wn = (wave & 3) * 64;
    const int q2 = lane >> 5, r32 = lane & 31;

    const long zA = (long)blockIdx.z * sA;
    const long zB = (long)blockIdx.z * sB;
    const long zC = (long)blockIdx.z * sC;
    const float sc = (blockIdx.y * 2 < gridDim.y) ? scale : scale2;

    // staging: thread t covers row t>>2 (+128 for 2nd group), phys chunk t&3,
    // fetching logical chunk ((t&3) - (t>>3) - (t>>6)) & 3.
    const int trow = tid >> 2;
    const int tcol = (((tid & 3) - ((tid >> 3) & 3) - ((tid >> 6) & 3)) & 3) * 8;
    const _Float16* gA0 = A0 + zA + (long)(blockIdx.x * 256 + trow) * lda + tcol;
    const _Float16* gB0 = B0 + zB + (long)(blockIdx.y * 256 + trow) * ldb + tcol;
    const _Float16* gA1 = A1 + zA + (long)(blockIdx.x * 256 + trow) * lda + tcol;
    const _Float16* gB1 = B1 + zB + (long)(blockIdx.y * 256 + trow) * ldb + tcol;

    const int ldsoff = tid * 8;  // halves; *2B = tid*16 bytes
    const int fbase = q2 + (r32 >> 1) + (r32 >> 4);

    f32x16 acc[4][2];
#pragma unroll
    for (int i = 0; i < 4; ++i)
#pragma unroll
        for (int j = 0; j < 2; ++j)
#pragma unroll
            for (int r = 0; r < 16; ++r) acc[i][j][r] = 0.f;

    const int nT = K >> 5;

    // prologue: stage tile 0 into buf 0, drain, barrier
    {
        _Float16* s = smem;
        stage_tile(s + 0, gA0, lda, ldsoff);
        stage_tile(s + 8192, gB0, ldb, ldsoff);
        stage_tile(s + 16384, gA1, lda, ldsoff);
        stage_tile(s + 24576, gB1, ldb, ldsoff);
        gA0 += 32; gB0 += 32; gA1 += 32; gB1 += 32;
        vmwait<0>();
        __builtin_amdgcn_s_barrier();
    }

    int buf = 0;
    for (int t = 0; t < nT; ++t) {
        _Float16* scur = smem + buf * 32768;
        _Float16* snx = smem + (buf ^ 1) * 32768;
        const bool pre = (t + 1 < nT);

        half8 a0[4][2], b0[2][2], a1[4][2], b1[2][2];

        // ---- P0: A0*B0; front-load ALL next-tile staging here ----
        ld_a(a0, scur, wm, r32, fbase);
        ld_b(b0, scur + 8192, wn, r32, fbase);
        if (pre) {
            stage_tile(snx + 0, gA0, lda, ldsoff);
            stage_tile(snx + 8192, gB0, ldb, ldsoff);
            stage_tile(snx + 16384, gA1, lda, ldsoff);
            stage_tile(snx + 24576, gB1, ldb, ldsoff);
            gA0 += 32; gB0 += 32; gA1 += 32; gB1 += 32;
        }
        __builtin_amdgcn_s_barrier();
        lgkm0_pin();
        __builtin_amdgcn_s_setprio(1);
        mfma_blk(acc, a0, b0);
        __builtin_amdgcn_s_setprio(0);
        __builtin_amdgcn_s_barrier();

        // ---- P1: A0*B1 ----
        ld_b(b1, scur + 24576, wn, r32, fbase);
        __builtin_amdgcn_s_barrier();
        lgkm0_pin();
        __builtin_amdgcn_s_setprio(1);
        mfma_blk(acc, a0, b1);
        __builtin_amdgcn_s_setprio(0);
        __builtin_amdgcn_s_barrier();

        // ---- P2: A1*B0 (b0 held in regs since P0) ----
        ld_a(a1, scur + 16384, wm, r32, fbase);
        __builtin_amdgcn_s_barrier();
        lgkm0_pin();
        __builtin_amdgcn_s_setprio(1);
        mfma_blk(acc, a1, b0);
        __builtin_amdgcn_s_setprio(0);
        if (pre) vmwait<0>();  // next-tile loads are ~2.5 phases old by now
        __builtin_amdgcn_s_barrier();

        buf ^= 1;
    }

    // epilogue: C/D layout col=lane&31, row=(reg&3)+8*(reg>>2)+4*q2
    const int crow0 = blockIdx.x * 256 + wm + 4 * q2;
    const int ccol0 = blockIdx.y * 256 + wn + r32;
#pragma unroll
    for (int i = 0; i < 4; ++i)
#pragma unroll
        for (int j = 0; j < 2; ++j)
#pragma unroll
            for (int r = 0; r < 16; ++r) {
                int row = crow0 + i * 32 + (r & 3) + 8 * (r >> 2);
                long off = zC + (long)row * ldc + (ccol0 + j * 32);
                float v = acc[i][j][r] * sc;
                if (OUTMODE == 0) {
                    Cf[off] = v;
                } else {
                    _Float16 h = (_Float16)v;
                    C0[off] = h;
                    C1[off] = (_Float16)(v - (float)h);
                }
            }
}

// ---------------------------------------------------------------------------
// Fused prep: blocks [0, NSPLIT) do the x fp32 -> f16 hi/lo split (x4 vec);
// blocks [NSPLIT, NSPLIT+3072) transpose+split the three weight matrices.
// ---------------------------------------------------------------------------
__global__ __launch_bounds__(256) void prep_fused(
    const float* __restrict__ x, _Float16* __restrict__ x0, _Float16* __restrict__ x1,
    long n4, int nsplit,
    const float* __restrict__ wq, const float* __restrict__ wk,
    const float* __restrict__ wv,
    _Float16* __restrict__ qk0, _Float16* __restrict__ qk1,
    _Float16* __restrict__ v0, _Float16* __restrict__ v1) {
    __shared__ float t[32][33];
    if ((int)blockIdx.x < nsplit) {
        long i = (long)blockIdx.x * 256 + threadIdx.x;
        if (i >= n4) return;
        float4 v = ((const float4*)x)[i];
        float a[4] = {v.x, v.y, v.z, v.w};
        half4v h, l;
#pragma unroll
        for (int c = 0; c < 4; ++c) {
            h[c] = (_Float16)a[c];
            l[c] = (_Float16)(a[c] - (float)h[c]);
        }
        ((half4v*)x0)[i] = h;
        ((half4v*)x1)[i] = l;
        return;
    }
    const int idx = blockIdx.x - nsplit;
    const int z = idx >> 10;
    const int tile = idx & 1023;
    const float* in = (z == 0) ? wq : (z == 1) ? wk : wv;
    _Float16* o0 = (z == 0) ? qk0 : (z == 1) ? qk0 + 1024 * 1024 : v0;
    _Float16* o1 = (z == 0) ? qk1 : (z == 1) ? qk1 + 1024 * 1024 : v1;

    const int c0 = (tile & 31) * 32, r0 = (tile >> 5) * 32;
    const int tx = threadIdx.x & 31, ty = threadIdx.x >> 5;
#pragma unroll
    for (int i = 0; i < 32; i += 8)
        t[ty + i][tx] = in[(long)(r0 + ty + i) * 1024 + c0 + tx];
    __syncthreads();
#pragma unroll
    for (int i = 0; i < 32; i += 8) {
        float v = t[tx][ty + i];
        _Float16 h = (_Float16)v;
        long o = (long)(c0 + ty + i) * 1024 + r0 + tx;
        o0[o] = h;
        o1[o] = (_Float16)(v - (float)h);
    }
}

// ---------------------------------------------------------------------------
// row softmax: S fp32 [8192][2048] -> P f16, one block per row (vectorized)
// ---------------------------------------------------------------------------
__global__ __launch_bounds__(256) void softmax_rows(const float* __restrict__ S,
                                                    _Float16* __restrict__ P) {
    const int n = 2048;
    const long base = (long)blockIdx.x * n;
    const float4* row4 = (const float4*)(S + base);
    const int tid = threadIdx.x;
    const int wave = tid >> 6;

    float4 v0 = row4[tid * 2];
    float4 v1 = row4[tid * 2 + 1];
    float v[8] = {v0.x, v0.y, v0.z, v0.w, v1.x, v1.y, v1.z, v1.w};
    float lm = -3.4e38f;
#pragma unroll
    for (int t = 0; t < 8; ++t) lm = fmaxf(lm, v[t]);
#pragma unroll
    for (int o = 32; o > 0; o >>= 1) lm = fmaxf(lm, __shfl_xor(lm, o));
    __shared__ float redm[4];
    __shared__ float reds[4];
    if ((tid & 63) == 0) redm[wave] = lm;
    __syncthreads();
    lm = fmaxf(fmaxf(redm[0], redm[1]), fmaxf(redm[2], redm[3]));

    float e[8];
    float ls = 0.f;
#pragma unroll
    for (int t = 0; t < 8; ++t) {
        e[t] = __expf(v[t] - lm);
        ls += e[t];
    }
#pragma unroll
    for (int o = 32; o > 0; o >>= 1) ls += __shfl_xor(ls, o);
    if ((tid & 63) == 0) reds[wave] = ls;
    __syncthreads();
    ls = reds[0] + reds[1] + reds[2] + reds[3];
    const float inv = 1.f / ls;
    half8 p;
#pragma unroll
    for (int t = 0; t < 8; ++t) p[t] = (_Float16)(e[t] * inv);
    ((half8*)(P + base))[tid] = p;
}

// ---------------------------------------------------------------------------
extern "C" void kernel_launch(void* const* d_in, const int* in_sizes, int n_in,
                              void* d_out, int out_size, void* d_ws, size_t ws_size,
                              hipStream_t stream) {
    (void)in_sizes; (void)n_in; (void)out_size; (void)ws_size;
    const float* x = (const float*)d_in[0];
    const float* wq = (const float*)d_in[1];
    const float* wk = (const float*)d_in[2];
    const float* wv = (const float*)d_in[3];
    float* out = (float*)d_out;
    char* ws = (char*)d_ws;

    const long MB = 1l << 20;
    // ws layout (188 MB):
    _Float16* Wqk0 = (_Float16*)(ws + 0 * MB);   // [2048][1024] 4 MB
    _Float16* Wqk1 = (_Float16*)(ws + 4 * MB);   // 4 MB
    _Float16* Wv0  = (_Float16*)(ws + 8 * MB);   // 2 MB
    _Float16* Wv1  = (_Float16*)(ws + 10 * MB);  // 2 MB (unused by NPROD=1 path)
    _Float16* x0   = (_Float16*)(ws + 12 * MB);  // 16 MB
    _Float16* x1   = (_Float16*)(ws + 28 * MB);  // 16 MB
    _Float16* P    = (_Float16*)(ws + 12 * MB);  // 32 MB, reuses dead x0/x1
    _Float16* QK0  = (_Float16*)(ws + 44 * MB);  // [8192][2048] 32 MB
    _Float16* QK1  = (_Float16*)(ws + 76 * MB);  // 32 MB
    _Float16* Vt   = (_Float16*)(ws + 108 * MB); // [1024][8192] 16 MB
    float*    S    = (float*)(ws + 124 * MB);    // 64 MB

    const int B = 4, SEQ = 2048, D = 1024;
    const long M = (long)B * SEQ;  // 8192
    const long ssq = (long)SEQ * SEQ;  // per-batch S stride
    const int nsplit = (int)((M * D / 4 + 255) / 256);  // 8192

    // 1) fused prep: x split + weight transpose/split (one dispatch)
    prep_fused<<<dim3(nsplit + 3072), dim3(256), 0, stream>>>(
        x, x0, x1, M * D / 4, nsplit, wq, wk, wv, Wqk0, Wqk1, Wv0, Wv1);

    // 2) fused Q|K projection (8-phase 256^2): QK[m][n], split out
    gemm8p<1><<<dim3(32, 8, 1), dim3(512), 0, stream>>>(
        x0, x1, Wqk0, Wqk1, nullptr, QK0, QK1, D, D, 2 * D, D,
        0, 0, 0, 0.03125f, 1.0f);

    // 3) V^T directly: Vt[e][m] = sum_d Wv^T[e][d] * x[m][d]  (NT, A=Wv^T, B=x)
    gemm_nt<1, 2><<<dim3(8, 64, 1), dim3(256), 0, stream>>>(
        Wv0, nullptr, x0, nullptr, nullptr, Vt, nullptr, D, D, (int)M, D,
        0, 0, 0, 1.0f, 1.0f);

    // 4) S = Qs @ K^T (8-phase 256^2, fp32 out; scaling folded into Q)
    gemm8p<0><<<dim3(8, 8, B), dim3(512), 0, stream>>>(
        QK0, QK1, QK0 + D, QK1 + D, S, nullptr, nullptr, 2 * D, 2 * D, SEQ, D,
        (long)SEQ * 2 * D, (long)SEQ * 2 * D, ssq, 1.0f, 1.0f);

    // 5) P = rowsoftmax(S) as f16
    softmax_rows<<<dim3(B * SEQ), dim3(256), 0, stream>>>(S, P);

    // 6) out = P @ V = P @ (Vt batch-view)^T ; Vt batch b = cols b*2048..
    gemm_nt<1, 0><<<dim3(16, 8, B), dim3(256), 0, stream>>>(
        P, nullptr, Vt, nullptr, out, nullptr, nullptr, SEQ, (int)M, D, SEQ,
        ssq, (long)SEQ, (long)SEQ * D, 1.0f, 1.0f);
}

// Round 2
// 362.792 us; speedup vs baseline: 1.0885x; 1.0530x over previous
//
#include <hip/hip_runtime.h>
#include <hip/hip_bf16.h>

// HybridSelfAttention: out = softmax((xWq)(xWk)^T / sqrt(d)) (xWv)
// B=4, S=2048, D=1024, fp32 in/out.
//
// Precision: f16 hi/lo split + 3-product MFMA for xWq, xWk, QK^T (softmax is
// near-one-hot; S must be ~fp32-accurate). Plain f16 MFMA for V^T and PV.
//
// R1: LDS chunk swizzle -> bank conflicts 8.4M -> 0.
// R2: dispatch fusion (QK proj fused, V^T direct GEMM, weight prep merged).
// R3: MFMA 32x32x16.
// R5: swizzle fix f(r)=((r>>1)+(r>>4))&3 -> conflicts 0.
// R6/R7: register-staging transport -> compiler spilled -> dead end.
// R8: double-buffered LDS, one barrier per K-iter -> 888 TF effective.
// R9: 256^2 8-wave 3-phase port -> only 977 TF (MfmaUtil 44). Post-mortem:
//   both gemm8p dispatches identical dur despite different layouts ->
//   structural stall. Coarse phases (512-cyc MFMA clusters, 12-read drains)
//   serialize LDS drain against MFMA windows: 3072 (MFMA) + ~2300 (LDS) +
//   barriers ~= 7920 cyc/step observed.
// R10: m201-faithful granularity: MFMA 16x16x32 (128-cyc clusters), 5 phases
//   per K-step {4-8 ds_read; <=2 stage; barrier; lgkmcnt(0)+sched_barrier;
//   setprio(1) 16 MFMA setprio(0); barrier}, stages spread P0-P2 oldest-first,
//   single vmcnt(0) at P4 (waits only >=2-phase-old loads). Swizzle for
//   16-row frags: phys chunk = (lc + fragidx + (lane&15)>>1) & 3 ->
//   verified conflict-free (each 4-bank group hit exactly 8x per b128).

typedef _Float16 half8 __attribute__((ext_vector_type(8)));
typedef _Float16 half4v __attribute__((ext_vector_type(4)));
typedef float f32x16 __attribute__((ext_vector_type(16)));
typedef float f32x4 __attribute__((ext_vector_type(4)));

#define GLOBAL_AS __attribute__((address_space(1)))
#define LDS_AS __attribute__((address_space(3)))

__device__ __forceinline__ void gll16(const _Float16* g, _Float16* l) {
    // async global->LDS DMA, 16B per lane; LDS dest is wave-uniform base + lane*16
    __builtin_amdgcn_global_load_lds((GLOBAL_AS const void*)g, (LDS_AS void*)l, 16, 0, 0);
}

__device__ __forceinline__ void lgkm0_pin() {
    // rule 18: sched_barrier(0) right after an inline-asm lgkmcnt wait, else
    // hipcc can hoist register-only MFMA above the wait.
    asm volatile("s_waitcnt lgkmcnt(0)" ::: "memory");
    __builtin_amdgcn_sched_barrier(0);
}

__device__ __forceinline__ void vmwait0() {
    asm volatile("s_waitcnt vmcnt(0)" ::: "memory");
}

// ---------------------------------------------------------------------------
// OLD 128x128 kernel (R8 structure) -- kept for the NPROD=1 ops (V^T, PV),
// whose grids would under-fill the chip at 256^2 tiles.
// ---------------------------------------------------------------------------
template <int NPROD, int OUTMODE>
__global__ __launch_bounds__(256) void gemm_nt(
    const _Float16* __restrict__ A0, const _Float16* __restrict__ A1,
    const _Float16* __restrict__ B0, const _Float16* __restrict__ B1,
    float* __restrict__ Cf, _Float16* __restrict__ C0, _Float16* __restrict__ C1,
    int lda, int ldb, int ldc, int K,
    long sA, long sB, long sC, float scale, float scale2) {
    constexpr int NTILES = (NPROD == 3) ? 4 : 2;
    constexpr int BUFH = NTILES * 4096;  // halves per buffer set
    __shared__ alignas(16) _Float16 smem[2 * BUFH];  // double-buffered tile sets

    const int tid = threadIdx.x;
    const int wave = tid >> 6, lane = tid & 63;
    const int wm = (wave >> 1) * 64, wn = (wave & 1) * 64;
    const int q2 = lane >> 5, r32 = lane & 31;

    const long zA = (long)blockIdx.z * sA;
    const long zB = (long)blockIdx.z * sB;
    const long zC = (long)blockIdx.z * sC;

    const float sc = (blockIdx.y * 2 < gridDim.y) ? scale : scale2;

    const int trow = tid >> 2;
    const int tcol = (((tid & 3) - ((tid >> 3) & 3) - ((tid >> 6) & 3)) & 3) * 8;
    const _Float16* gA0 = A0 + zA + (long)(blockIdx.x * 128 + trow) * lda + tcol;
    const _Float16* gB0 = B0 + zB + (long)(blockIdx.y * 128 + trow) * ldb + tcol;
    const _Float16* gA1 = (NPROD == 3) ? (A1 + zA + (long)(blockIdx.x * 128 + trow) * lda + tcol) : nullptr;
    const _Float16* gB1 = (NPROD == 3) ? (B1 + zB + (long)(blockIdx.y * 128 + trow) * ldb + tcol) : nullptr;

    f32x16 acc[2][2];
#pragma unroll
    for (int i = 0; i < 2; ++i)
#pragma unroll
        for (int j = 0; j < 2; ++j)
#pragma unroll
            for (int r = 0; r < 16; ++r) acc[i][j][r] = 0.f;

    const int ldsoff = tid * 8;
    const int fbase = q2 + (r32 >> 1) + (r32 >> 4);

    {
        _Float16* s = smem;
        gll16(gA0, s + ldsoff);
        gll16(gA0 + 64 * lda, s + ldsoff + 2048);
        gll16(gB0, s + 4096 + ldsoff);
        gll16(gB0 + 64 * ldb, s + 4096 + ldsoff + 2048);
        if (NPROD == 3) {
            gll16(gA1, s + 8192 + ldsoff);
            gll16(gA1 + 64 * lda, s + 8192 + ldsoff + 2048);
            gll16(gB1, s + 12288 + ldsoff);
            gll16(gB1 + 64 * ldb, s + 12288 + ldsoff + 2048);
        }
        gA0 += 32; gB0 += 32;
        if (NPROD == 3) { gA1 += 32; gB1 += 32; }
    }

    int buf = 0;
    for (int k0 = 0; k0 < K; k0 += 32) {
        __syncthreads();

        if (k0 + 32 < K) {
            _Float16* s = smem + (buf ^ 1) * BUFH;
            gll16(gA0, s + ldsoff);
            gll16(gA0 + 64 * lda, s + ldsoff + 2048);
            gll16(gB0, s + 4096 + ldsoff);
            gll16(gB0 + 64 * ldb, s + 4096 + ldsoff + 2048);
            if (NPROD == 3) {
                gll16(gA1, s + 8192 + ldsoff);
                gll16(gA1 + 64 * lda, s + 8192 + ldsoff + 2048);
                gll16(gB1, s + 12288 + ldsoff);
                gll16(gB1 + 64 * ldb, s + 12288 + ldsoff + 2048);
            }
            gA0 += 32; gB0 += 32;
            if (NPROD == 3) { gA1 += 32; gB1 += 32; }
        }

        _Float16* sA0 = smem + buf * BUFH;
        _Float16* sB0 = sA0 + 4096;
        _Float16* sA1 = (NPROD == 3) ? sA0 + 8192 : sA0;
        _Float16* sB1 = (NPROD == 3) ? sA0 + 12288 : sA0;
#pragma unroll
        for (int h = 0; h < 2; ++h) {
            half8 a0[2], b0[2], a1[2], b1[2];
#pragma unroll
            for (int i = 0; i < 2; ++i) {
                const int pp = ((fbase + 2 * i + 2 * h) & 3) * 8;
                a0[i] = *(const half8*)(sA0 + (wm + i * 32 + r32) * 32 + pp);
                b0[i] = *(const half8*)(sB0 + (wn + i * 32 + r32) * 32 + pp);
                if (NPROD == 3) {
                    a1[i] = *(const half8*)(sA1 + (wm + i * 32 + r32) * 32 + pp);
                    b1[i] = *(const half8*)(sB1 + (wn + i * 32 + r32) * 32 + pp);
                }
            }
#pragma unroll
            for (int i = 0; i < 2; ++i)
#pragma unroll
                for (int j = 0; j < 2; ++j) {
                    acc[i][j] = __builtin_amdgcn_mfma_f32_32x32x16_f16(a0[i], b0[j], acc[i][j], 0, 0, 0);
                    if (NPROD == 3) {
                        acc[i][j] = __builtin_amdgcn_mfma_f32_32x32x16_f16(a0[i], b1[j], acc[i][j], 0, 0, 0);
                        acc[i][j] = __builtin_amdgcn_mfma_f32_32x32x16_f16(a1[i], b0[j], acc[i][j], 0, 0, 0);
                    }
                }
        }
        buf ^= 1;
    }

    const int crow0 = blockIdx.x * 128 + wm + 4 * q2;
    const int ccol0 = blockIdx.y * 128 + wn + r32;
#pragma unroll
    for (int i = 0; i < 2; ++i)
#pragma unroll
        for (int j = 0; j < 2; ++j)
#pragma unroll
            for (int r = 0; r < 16; ++r) {
                int row = crow0 + i * 32 + (r & 3) + 8 * (r >> 2);
                long off = zC + (long)row * ldc + (ccol0 + j * 32);
                float v = acc[i][j][r] * sc;
                if (OUTMODE == 0) {
                    Cf[off] = v;
                } else if (OUTMODE == 2) {
                    C0[off] = (_Float16)v;
                } else {
                    _Float16 h = (_Float16)v;
                    C0[off] = h;
                    C1[off] = (_Float16)(v - (float)h);
                }
            }
}

// ---------------------------------------------------------------------------
// 256x256-tile, 8-wave, 5-phase NT GEMM (m201-faithful granularity) for the
// NPROD=3 products.  C[M,N] = (A0+A1)(B0+B1)^T ~= A0B0 + A0B1 + A1B0.
// 512 thr = 8 waves (2 M x 4 N), per-wave 128x64 output, acc = 32 x f32x4.
// MFMA 16x16x32_f16: A/B frag row/col = lane&15, k = (lane>>4)*8 + e.
// C/D frag: col = lane&15, row = (lane>>4)*4 + reg.
// BK=32; LDS: 2 bufs x {A0,B0,A1,B1} x [256][32] f16 = 128 KiB.
// Phases per K-step (16 MFMA = 128 cyc/wave each, except P4 = 32):
//   P0: read a0L(4)+b0(4), stage A0(2) | P1: read a0H(4), stage B0(2)
//   P2: read b1(4), stage A1(2)+B1(2)  | P3: read a1L(4)
//   P4: read a1H(4), MFMA x32, vmcnt(0)
// Each phase: {reads; stages; s_barrier; lgkmcnt(0)+sched_barrier;
//   setprio(1) MFMA setprio(0); s_barrier}.
// Swizzle: physical chunk p of row r = (c + f(r))&3, f(r)=((r>>1)+(r>>4))&3.
// For a 16-row fragment at base FB (FB%16==0): f reduces to
//   (FB>>4 + ((lane&15)>>1)) & 3  -> conflict-free (each 4-bank group 8x).
// ---------------------------------------------------------------------------
__device__ __forceinline__ int frag_off(int fb, int lrow, int lc) {
    // offset in halves within a [256][32] tile for fragment base row fb
    return (fb + lrow) * 32 + ((((fb >> 4) + lc + (lrow >> 1)) & 3) << 3);
}

__device__ __forceinline__ void ld4(half8 (&d)[4], const _Float16* base, int fb0,
                                    int lrow, int lc) {
#pragma unroll
    for (int f = 0; f < 4; ++f)
        d[f] = *(const half8*)(base + frag_off(fb0 + 16 * f, lrow, lc));
}

template <int MH>
__device__ __forceinline__ void mm16(f32x4 (&acc)[8][4], const half8 (&a)[4],
                                     const half8 (&b)[4]) {
#pragma unroll
    for (int i = 0; i < 4; ++i)
#pragma unroll
        for (int j = 0; j < 4; ++j)
            acc[MH * 4 + i][j] =
                __builtin_amdgcn_mfma_f32_16x16x32_f16(a[i], b[j], acc[MH * 4 + i][j], 0, 0, 0);
}

__device__ __forceinline__ void stage_tile(_Float16* dst, const _Float16* g, int ld,
                                           int ldsoff) {
    // [256][32] f16 tile = 2 gll16 groups of 128 rows (512 thr x 16B each)
    gll16(g, dst + ldsoff);
    gll16(g + (long)128 * ld, dst + 4096 + ldsoff);
}

template <int OUTMODE>
__global__ __launch_bounds__(512, 2) void gemm5p(
    const _Float16* __restrict__ A0, const _Float16* __restrict__ A1,
    const _Float16* __restrict__ B0, const _Float16* __restrict__ B1,
    float* __restrict__ Cf, _Float16* __restrict__ C0, _Float16* __restrict__ C1,
    int lda, int ldb, int ldc, int K,
    long sA, long sB, long sC, float scale, float scale2) {
    __shared__ alignas(16) _Float16 smem[65536];  // 128 KiB: 2 x {A0,B0,A1,B1}

    const int tid = threadIdx.x;
    const int wave = tid >> 6, lane = tid & 63;
    const int wm = (wave >> 2) * 128, wn = (wave & 3) * 64;
    const int lrow = lane & 15, lc = lane >> 4;

    const long zA = (long)blockIdx.z * sA;
    const long zB = (long)blockIdx.z * sB;
    const long zC = (long)blockIdx.z * sC;
    const float sc = (blockIdx.y * 2 < gridDim.y) ? scale : scale2;

    // staging: thread t covers row t>>2 (+128 for 2nd group), phys chunk t&3,
    // fetching logical chunk ((t&3) - f(t>>2)) & 3; f(r+128)==f(r) mod 4.
    const int trow = tid >> 2;
    const int tcol = (((tid & 3) - ((tid >> 3) & 3) - ((tid >> 6) & 3)) & 3) * 8;
    const _Float16* gA0 = A0 + zA + (long)(blockIdx.x * 256 + trow) * lda + tcol;
    const _Float16* gB0 = B0 + zB + (long)(blockIdx.y * 256 + trow) * ldb + tcol;
    const _Float16* gA1 = A1 + zA + (long)(blockIdx.x * 256 + trow) * lda + tcol;
    const _Float16* gB1 = B1 + zB + (long)(blockIdx.y * 256 + trow) * ldb + tcol;

    const int ldsoff = tid * 8;  // halves; *2B = tid*16 bytes

    f32x4 acc[8][4];
#pragma unroll
    for (int i = 0; i < 8; ++i)
#pragma unroll
        for (int j = 0; j < 4; ++j)
#pragma unroll
            for (int r = 0; r < 4; ++r) acc[i][j][r] = 0.f;

    const int nT = K >> 5;

    // prologue: stage tile 0 into buf 0, drain, barrier
    {
        _Float16* s = smem;
        stage_tile(s + 0, gA0, lda, ldsoff);
        stage_tile(s + 8192, gB0, ldb, ldsoff);
        stage_tile(s + 16384, gA1, lda, ldsoff);
        stage_tile(s + 24576, gB1, ldb, ldsoff);
        gA0 += 32; gB0 += 32; gA1 += 32; gB1 += 32;
        vmwait0();
        __builtin_amdgcn_s_barrier();
    }

    int buf = 0;
    for (int t = 0; t < nT; ++t) {
        _Float16* scur = smem + buf * 32768;
        _Float16* snx = smem + (buf ^ 1) * 32768;
        const bool pre = (t + 1 < nT);

        half8 a0L[4], a0H[4], a1L[4], a1H[4], b0[4], b1[4];

        // ---- P0: a0L x b0 ----
        ld4(a0L, scur, wm, lrow, lc);
        ld4(b0, scur + 8192, wn, lrow, lc);
        if (pre) { stage_tile(snx + 0, gA0, lda, ldsoff); gA0 += 32; }
        __builtin_amdgcn_s_barrier();
        lgkm0_pin();
        __builtin_amdgcn_s_setprio(1);
        mm16<0>(acc, a0L, b0);
        __builtin_amdgcn_s_setprio(0);
        __builtin_amdgcn_s_barrier();

        // ---- P1: a0H x b0 ----
        ld4(a0H, scur, wm + 64, lrow, lc);
        if (pre) { stage_tile(snx + 8192, gB0, ldb, ldsoff); gB0 += 32; }
        __builtin_amdgcn_s_barrier();
        lgkm0_pin();
        __builtin_amdgcn_s_setprio(1);
        mm16<1>(acc, a0H, b0);
        __builtin_amdgcn_s_setprio(0);
        __builtin_amdgcn_s_barrier();

        // ---- P2: a0H x b1 ----
        ld4(b1, scur + 24576, wn, lrow, lc);
        if (pre) {
            stage_tile(snx + 16384, gA1, lda, ldsoff); gA1 += 32;
            stage_tile(snx + 24576, gB1, ldb, ldsoff); gB1 += 32;
        }
        __builtin_amdgcn_s_barrier();
        lgkm0_pin();
        __builtin_amdgcn_s_setprio(1);
        mm16<1>(acc, a0H, b1);
        __builtin_amdgcn_s_setprio(0);
        __builtin_amdgcn_s_barrier();

        // ---- P3: a0L x b1 ----
        ld4(a1L, scur + 16384, wm, lrow, lc);
        __builtin_amdgcn_s_barrier();
        lgkm0_pin();
        __builtin_amdgcn_s_setprio(1);
        mm16<0>(acc, a0L, b1);
        __builtin_amdgcn_s_setprio(0);
        __builtin_amdgcn_s_barrier();

        // ---- P4: a1L x b0, a1H x b0 ----
        ld4(a1H, scur + 16384, wm + 64, lrow, lc);
        __builtin_amdgcn_s_barrier();
        lgkm0_pin();
        __builtin_amdgcn_s_setprio(1);
        mm16<0>(acc, a1L, b0);
        mm16<1>(acc, a1H, b0);
        __builtin_amdgcn_s_setprio(0);
        if (pre) vmwait0();  // oldest stage (A0) is 4+ phases old; newest 2+
        __builtin_amdgcn_s_barrier();

        buf ^= 1;
    }

    // epilogue: C/D layout col=lane&15, row=(lane>>4)*4+reg
    const int crow0 = blockIdx.x * 256 + wm + lc * 4;
    const int ccol0 = blockIdx.y * 256 + wn + lrow;
#pragma unroll
    for (int mf = 0; mf < 8; ++mf)
#pragma unroll
        for (int nf = 0; nf < 4; ++nf)
#pragma unroll
            for (int r = 0; r < 4; ++r) {
                int row = crow0 + mf * 16 + r;
                long off = zC + (long)row * ldc + (ccol0 + nf * 16);
                float v = acc[mf][nf][r] * sc;
                if (OUTMODE == 0) {
                    Cf[off] = v;
                } else {
                    _Float16 h = (_Float16)v;
                    C0[off] = h;
                    C1[off] = (_Float16)(v - (float)h);
                }
            }
}

// ---------------------------------------------------------------------------
// Fused prep: blocks [0, NSPLIT) do the x fp32 -> f16 hi/lo split (x4 vec);
// blocks [NSPLIT, NSPLIT+3072) transpose+split the three weight matrices.
// ---------------------------------------------------------------------------
__global__ __launch_bounds__(256) void prep_fused(
    const float* __restrict__ x, _Float16* __restrict__ x0, _Float16* __restrict__ x1,
    long n4, int nsplit,
    const float* __restrict__ wq, const float* __restrict__ wk,
    const float* __restrict__ wv,
    _Float16* __restrict__ qk0, _Float16* __restrict__ qk1,
    _Float16* __restrict__ v0, _Float16* __restrict__ v1) {
    __shared__ float t[32][33];
    if ((int)blockIdx.x < nsplit) {
        long i = (long)blockIdx.x * 256 + threadIdx.x;
        if (i >= n4) return;
        float4 v = ((const float4*)x)[i];
        float a[4] = {v.x, v.y, v.z, v.w};
        half4v h, l;
#pragma unroll
        for (int c = 0; c < 4; ++c) {
            h[c] = (_Float16)a[c];
            l[c] = (_Float16)(a[c] - (float)h[c]);
        }
        ((half4v*)x0)[i] = h;
        ((half4v*)x1)[i] = l;
        return;
    }
    const int idx = blockIdx.x - nsplit;
    const int z = idx >> 10;
    const int tile = idx & 1023;
    const float* in = (z == 0) ? wq : (z == 1) ? wk : wv;
    _Float16* o0 = (z == 0) ? qk0 : (z == 1) ? qk0 + 1024 * 1024 : v0;
    _Float16* o1 = (z == 0) ? qk1 : (z == 1) ? qk1 + 1024 * 1024 : v1;

    const int c0 = (tile & 31) * 32, r0 = (tile >> 5) * 32;
    const int tx = threadIdx.x & 31, ty = threadIdx.x >> 5;
#pragma unroll
    for (int i = 0; i < 32; i += 8)
        t[ty + i][tx] = in[(long)(r0 + ty + i) * 1024 + c0 + tx];
    __syncthreads();
#pragma unroll
    for (int i = 0; i < 32; i += 8) {
        float v = t[tx][ty + i];
        _Float16 h = (_Float16)v;
        long o = (long)(c0 + ty + i) * 1024 + r0 + tx;
        o0[o] = h;
        o1[o] = (_Float16)(v - (float)h);
    }
}

// ---------------------------------------------------------------------------
// row softmax: S fp32 [8192][2048] -> P f16, one block per row (vectorized)
// ---------------------------------------------------------------------------
__global__ __launch_bounds__(256) void softmax_rows(const float* __restrict__ S,
                                                    _Float16* __restrict__ P) {
    const int n = 2048;
    const long base = (long)blockIdx.x * n;
    const float4* row4 = (const float4*)(S + base);
    const int tid = threadIdx.x;
    const int wave = tid >> 6;

    float4 v0 = row4[tid * 2];
    float4 v1 = row4[tid * 2 + 1];
    float v[8] = {v0.x, v0.y, v0.z, v0.w, v1.x, v1.y, v1.z, v1.w};
    float lm = -3.4e38f;
#pragma unroll
    for (int t = 0; t < 8; ++t) lm = fmaxf(lm, v[t]);
#pragma unroll
    for (int o = 32; o > 0; o >>= 1) lm = fmaxf(lm, __shfl_xor(lm, o));
    __shared__ float redm[4];
    __shared__ float reds[4];
    if ((tid & 63) == 0) redm[wave] = lm;
    __syncthreads();
    lm = fmaxf(fmaxf(redm[0], redm[1]), fmaxf(redm[2], redm[3]));

    float e[8];
    float ls = 0.f;
#pragma unroll
    for (int t = 0; t < 8; ++t) {
        e[t] = __expf(v[t] - lm);
        ls += e[t];
    }
#pragma unroll
    for (int o = 32; o > 0; o >>= 1) ls += __shfl_xor(ls, o);
    if ((tid & 63) == 0) reds[wave] = ls;
    __syncthreads();
    ls = reds[0] + reds[1] + reds[2] + reds[3];
    const float inv = 1.f / ls;
    half8 p;
#pragma unroll
    for (int t = 0; t < 8; ++t) p[t] = (_Float16)(e[t] * inv);
    ((half8*)(P + base))[tid] = p;
}

// ---------------------------------------------------------------------------
extern "C" void kernel_launch(void* const* d_in, const int* in_sizes, int n_in,
                              void* d_out, int out_size, void* d_ws, size_t ws_size,
                              hipStream_t stream) {
    (void)in_sizes; (void)n_in; (void)out_size; (void)ws_size;
    const float* x = (const float*)d_in[0];
    const float* wq = (const float*)d_in[1];
    const float* wk = (const float*)d_in[2];
    const float* wv = (const float*)d_in[3];
    float* out = (float*)d_out;
    char* ws = (char*)d_ws;

    const long MB = 1l << 20;
    // ws layout (188 MB):
    _Float16* Wqk0 = (_Float16*)(ws + 0 * MB);   // [2048][1024] 4 MB
    _Float16* Wqk1 = (_Float16*)(ws + 4 * MB);   // 4 MB
    _Float16* Wv0  = (_Float16*)(ws + 8 * MB);   // 2 MB
    _Float16* Wv1  = (_Float16*)(ws + 10 * MB);  // 2 MB (unused by NPROD=1 path)
    _Float16* x0   = (_Float16*)(ws + 12 * MB);  // 16 MB
    _Float16* x1   = (_Float16*)(ws + 28 * MB);  // 16 MB
    _Float16* P    = (_Float16*)(ws + 12 * MB);  // 32 MB, reuses dead x0/x1
    _Float16* QK0  = (_Float16*)(ws + 44 * MB);  // [8192][2048] 32 MB
    _Float16* QK1  = (_Float16*)(ws + 76 * MB);  // 32 MB
    _Float16* Vt   = (_Float16*)(ws + 108 * MB); // [1024][8192] 16 MB
    float*    S    = (float*)(ws + 124 * MB);    // 64 MB

    const int B = 4, SEQ = 2048, D = 1024;
    const long M = (long)B * SEQ;  // 8192
    const long ssq = (long)SEQ * SEQ;  // per-batch S stride
    const int nsplit = (int)((M * D / 4 + 255) / 256);  // 8192

    // 1) fused prep: x split + weight transpose/split (one dispatch)
    prep_fused<<<dim3(nsplit + 3072), dim3(256), 0, stream>>>(
        x, x0, x1, M * D / 4, nsplit, wq, wk, wv, Wqk0, Wqk1, Wv0, Wv1);

    // 2) fused Q|K projection (5-phase 256^2): QK[m][n], split out
    gemm5p<1><<<dim3(32, 8, 1), dim3(512), 0, stream>>>(
        x0, x1, Wqk0, Wqk1, nullptr, QK0, QK1, D, D, 2 * D, D,
        0, 0, 0, 0.03125f, 1.0f);

    // 3) V^T directly: Vt[e][m] = sum_d Wv^T[e][d] * x[m][d]  (NT, A=Wv^T, B=x)
    gemm_nt<1, 2><<<dim3(8, 64, 1), dim3(256), 0, stream>>>(
        Wv0, nullptr, x0, nullptr, nullptr, Vt, nullptr, D, D, (int)M, D,
        0, 0, 0, 1.0f, 1.0f);

    // 4) S = Qs @ K^T (5-phase 256^2, fp32 out; scaling folded into Q)
    gemm5p<0><<<dim3(8, 8, B), dim3(512), 0, stream>>>(
        QK0, QK1, QK0 + D, QK1 + D, S, nullptr, nullptr, 2 * D, 2 * D, SEQ, D,
        (long)SEQ * 2 * D, (long)SEQ * 2 * D, ssq, 1.0f, 1.0f);

    // 5) P = rowsoftmax(S) as f16
    softmax_rows<<<dim3(B * SEQ), dim3(256), 0, stream>>>(S, P);

    // 6) out = P @ V = P @ (Vt batch-view)^T ; Vt batch b = cols b*2048..
    gemm_nt<1, 0><<<dim3(16, 8, B), dim3(256), 0, stream>>>(
        P, nullptr, Vt, nullptr, out, nullptr, nullptr, SEQ, (int)M, D, SEQ,
        ssq, (long)SEQ, (long)SEQ * D, 1.0f, 1.0f);
}

// Round 4
// 357.281 us; speedup vs baseline: 1.1053x; 1.0154x over previous
//
#include <hip/hip_runtime.h>
#include <hip/hip_bf16.h>

// HybridSelfAttention: out = softmax((xWq)(xWk)^T / sqrt(d)) (xWv)
// B=4, S=2048, D=1024, fp32 in/out.
//
// Precision: f16 hi/lo split + 3-product MFMA for xWq, xWk, QK^T (softmax is
// near-one-hot; S must be ~fp32-accurate). Plain f16 MFMA for V^T and PV.
//
// R1: LDS chunk swizzle -> bank conflicts 8.4M -> 0.
// R2: dispatch fusion (QK proj fused, V^T direct GEMM, weight prep merged).
// R3: MFMA 32x32x16.
// R5: swizzle fix f(r)=((r>>1)+(r>>4))&3 -> conflicts 0.
// R6/R7: register-staging transport -> compiler spilled -> dead end.
// R8: double-buffered LDS, one barrier per K-iter -> 888 TF effective.
// R9: 256^2 8-wave 3-phase port -> 977 TF (MfmaUtil 44): coarse phases
//   serialize LDS drain against MFMA windows.
// R10: m201 granularity (16x16x32, 5 phases, 16-MFMA clusters) -> 98 us,
//   MfmaUtil only 45.6. Post-mortem: "8-phase with drain-0" regime (m218):
//   the lone vmcnt(0) at P4 drains loads issued 2 phases earlier.
// R11: T4 counted vmcnt, never 0 in main loop. Load groups per step:
//   G0=A0@P0, G1=B0@P1, G2=A1,G3=B1@P2 (2 gll16 each). Waits:
//     end-P1: vmcnt(4) forces G2,G3(t), leaves G0,G1(t+1) in flight
//     end-P4: vmcnt(4) forces G0,G1(t+1), leaves G2,G3(t+1) in flight
//   Every waited-on load >=3 phases old.
// R12: resubmit of R11 -- bench infra failed twice (no dispatch profiled, no
//   correctness signal). Deadlock audit re-done: uniform barriers, vmcnt
//   ledger never below outstanding, WAR separated by phase barriers. Kernel
//   unchanged to keep the experiment single-variable.

typedef _Float16 half8 __attribute__((ext_vector_type(8)));
typedef _Float16 half4v __attribute__((ext_vector_type(4)));
typedef float f32x16 __attribute__((ext_vector_type(16)));
typedef float f32x4 __attribute__((ext_vector_type(4)));

#define GLOBAL_AS __attribute__((address_space(1)))
#define LDS_AS __attribute__((address_space(3)))

__device__ __forceinline__ void gll16(const _Float16* g, _Float16* l) {
    // async global->LDS DMA, 16B per lane; LDS dest is wave-uniform base + lane*16
    __builtin_amdgcn_global_load_lds((GLOBAL_AS const void*)g, (LDS_AS void*)l, 16, 0, 0);
}

__device__ __forceinline__ void lgkm0_pin() {
    // rule 18: sched_barrier(0) right after an inline-asm lgkmcnt wait, else
    // hipcc can hoist register-only MFMA above the wait.
    asm volatile("s_waitcnt lgkmcnt(0)" ::: "memory");
    __builtin_amdgcn_sched_barrier(0);
}

__device__ __forceinline__ void vmwait0() {
    asm volatile("s_waitcnt vmcnt(0)" ::: "memory");
}

__device__ __forceinline__ void vmwait4() {
    asm volatile("s_waitcnt vmcnt(4)" ::: "memory");
}

// ---------------------------------------------------------------------------
// OLD 128x128 kernel (R8 structure) -- kept for the NPROD=1 ops (V^T, PV),
// whose grids would under-fill the chip at 256^2 tiles.
// ---------------------------------------------------------------------------
template <int NPROD, int OUTMODE>
__global__ __launch_bounds__(256) void gemm_nt(
    const _Float16* __restrict__ A0, const _Float16* __restrict__ A1,
    const _Float16* __restrict__ B0, const _Float16* __restrict__ B1,
    float* __restrict__ Cf, _Float16* __restrict__ C0, _Float16* __restrict__ C1,
    int lda, int ldb, int ldc, int K,
    long sA, long sB, long sC, float scale, float scale2) {
    constexpr int NTILES = (NPROD == 3) ? 4 : 2;
    constexpr int BUFH = NTILES * 4096;  // halves per buffer set
    __shared__ alignas(16) _Float16 smem[2 * BUFH];  // double-buffered tile sets

    const int tid = threadIdx.x;
    const int wave = tid >> 6, lane = tid & 63;
    const int wm = (wave >> 1) * 64, wn = (wave & 1) * 64;
    const int q2 = lane >> 5, r32 = lane & 31;

    const long zA = (long)blockIdx.z * sA;
    const long zB = (long)blockIdx.z * sB;
    const long zC = (long)blockIdx.z * sC;

    const float sc = (blockIdx.y * 2 < gridDim.y) ? scale : scale2;

    const int trow = tid >> 2;
    const int tcol = (((tid & 3) - ((tid >> 3) & 3) - ((tid >> 6) & 3)) & 3) * 8;
    const _Float16* gA0 = A0 + zA + (long)(blockIdx.x * 128 + trow) * lda + tcol;
    const _Float16* gB0 = B0 + zB + (long)(blockIdx.y * 128 + trow) * ldb + tcol;
    const _Float16* gA1 = (NPROD == 3) ? (A1 + zA + (long)(blockIdx.x * 128 + trow) * lda + tcol) : nullptr;
    const _Float16* gB1 = (NPROD == 3) ? (B1 + zB + (long)(blockIdx.y * 128 + trow) * ldb + tcol) : nullptr;

    f32x16 acc[2][2];
#pragma unroll
    for (int i = 0; i < 2; ++i)
#pragma unroll
        for (int j = 0; j < 2; ++j)
#pragma unroll
            for (int r = 0; r < 16; ++r) acc[i][j][r] = 0.f;

    const int ldsoff = tid * 8;
    const int fbase = q2 + (r32 >> 1) + (r32 >> 4);

    {
        _Float16* s = smem;
        gll16(gA0, s + ldsoff);
        gll16(gA0 + 64 * lda, s + ldsoff + 2048);
        gll16(gB0, s + 4096 + ldsoff);
        gll16(gB0 + 64 * ldb, s + 4096 + ldsoff + 2048);
        if (NPROD == 3) {
            gll16(gA1, s + 8192 + ldsoff);
            gll16(gA1 + 64 * lda, s + 8192 + ldsoff + 2048);
            gll16(gB1, s + 12288 + ldsoff);
            gll16(gB1 + 64 * ldb, s + 12288 + ldsoff + 2048);
        }
        gA0 += 32; gB0 += 32;
        if (NPROD == 3) { gA1 += 32; gB1 += 32; }
    }

    int buf = 0;
    for (int k0 = 0; k0 < K; k0 += 32) {
        __syncthreads();

        if (k0 + 32 < K) {
            _Float16* s = smem + (buf ^ 1) * BUFH;
            gll16(gA0, s + ldsoff);
            gll16(gA0 + 64 * lda, s + ldsoff + 2048);
            gll16(gB0, s + 4096 + ldsoff);
            gll16(gB0 + 64 * ldb, s + 4096 + ldsoff + 2048);
            if (NPROD == 3) {
                gll16(gA1, s + 8192 + ldsoff);
                gll16(gA1 + 64 * lda, s + 8192 + ldsoff + 2048);
                gll16(gB1, s + 12288 + ldsoff);
                gll16(gB1 + 64 * ldb, s + 12288 + ldsoff + 2048);
            }
            gA0 += 32; gB0 += 32;
            if (NPROD == 3) { gA1 += 32; gB1 += 32; }
        }

        _Float16* sA0 = smem + buf * BUFH;
        _Float16* sB0 = sA0 + 4096;
        _Float16* sA1 = (NPROD == 3) ? sA0 + 8192 : sA0;
        _Float16* sB1 = (NPROD == 3) ? sA0 + 12288 : sA0;
#pragma unroll
        for (int h = 0; h < 2; ++h) {
            half8 a0[2], b0[2], a1[2], b1[2];
#pragma unroll
            for (int i = 0; i < 2; ++i) {
                const int pp = ((fbase + 2 * i + 2 * h) & 3) * 8;
                a0[i] = *(const half8*)(sA0 + (wm + i * 32 + r32) * 32 + pp);
                b0[i] = *(const half8*)(sB0 + (wn + i * 32 + r32) * 32 + pp);
                if (NPROD == 3) {
                    a1[i] = *(const half8*)(sA1 + (wm + i * 32 + r32) * 32 + pp);
                    b1[i] = *(const half8*)(sB1 + (wn + i * 32 + r32) * 32 + pp);
                }
            }
#pragma unroll
            for (int i = 0; i < 2; ++i)
#pragma unroll
                for (int j = 0; j < 2; ++j) {
                    acc[i][j] = __builtin_amdgcn_mfma_f32_32x32x16_f16(a0[i], b0[j], acc[i][j], 0, 0, 0);
                    if (NPROD == 3) {
                        acc[i][j] = __builtin_amdgcn_mfma_f32_32x32x16_f16(a0[i], b1[j], acc[i][j], 0, 0, 0);
                        acc[i][j] = __builtin_amdgcn_mfma_f32_32x32x16_f16(a1[i], b0[j], acc[i][j], 0, 0, 0);
                    }
                }
        }
        buf ^= 1;
    }

    const int crow0 = blockIdx.x * 128 + wm + 4 * q2;
    const int ccol0 = blockIdx.y * 128 + wn + r32;
#pragma unroll
    for (int i = 0; i < 2; ++i)
#pragma unroll
        for (int j = 0; j < 2; ++j)
#pragma unroll
            for (int r = 0; r < 16; ++r) {
                int row = crow0 + i * 32 + (r & 3) + 8 * (r >> 2);
                long off = zC + (long)row * ldc + (ccol0 + j * 32);
                float v = acc[i][j][r] * sc;
                if (OUTMODE == 0) {
                    Cf[off] = v;
                } else if (OUTMODE == 2) {
                    C0[off] = (_Float16)v;
                } else {
                    _Float16 h = (_Float16)v;
                    C0[off] = h;
                    C1[off] = (_Float16)(v - (float)h);
                }
            }
}

// ---------------------------------------------------------------------------
// 256x256-tile, 8-wave, 5-phase NT GEMM with counted vmcnt (T3+T4+T5) for the
// NPROD=3 products.  C[M,N] = (A0+A1)(B0+B1)^T ~= A0B0 + A0B1 + A1B0.
// 512 thr = 8 waves (2 M x 4 N), per-wave 128x64 output, acc = 32 x f32x4.
// MFMA 16x16x32_f16: A/B frag row/col = lane&15, k = (lane>>4)*8 + e.
// C/D frag: col = lane&15, row = (lane>>4)*4 + reg.
// BK=32; LDS: 2 bufs x {A0,B0,A1,B1} x [256][32] f16 = 128 KiB.
// Phases per K-step (16 MFMA each, P4 = 32):
//   P0: read a0L+b0, stage A0      | P1: read a0H, stage B0, vmcnt(4)
//   P2: read b1, stage A1+B1       | P3: read a1L
//   P4: read a1H, MFMA x32, vmcnt(4)
// Each phase: {reads; stages; s_barrier; lgkmcnt(0)+sched_barrier;
//   setprio(1) MFMA setprio(0); [vmcnt]; s_barrier}.
// Counted waits (oldest-retire): end-P1 vmcnt(4) forces A1,B1 of the CURRENT
// step (read at P2/P3) while the next step's A0,B0 stay in flight; end-P4
// vmcnt(4) forces next step's A0,B0 (read at its P0) while its A1,B1 fly.
// No vmcnt(0) in the main loop except the final iteration's end-P1 drain.
// Swizzle: physical chunk p of row r = (c + f(r))&3, f(r)=((r>>1)+(r>>4))&3.
// For a 16-row fragment at base FB (FB%16==0): f reduces to
//   (FB>>4 + ((lane&15)>>1)) & 3  -> conflict-free.
// ---------------------------------------------------------------------------
__device__ __forceinline__ int frag_off(int fb, int lrow, int lc) {
    // offset in halves within a [256][32] tile for fragment base row fb
    return (fb + lrow) * 32 + ((((fb >> 4) + lc + (lrow >> 1)) & 3) << 3);
}

__device__ __forceinline__ void ld4(half8 (&d)[4], const _Float16* base, int fb0,
                                    int lrow, int lc) {
#pragma unroll
    for (int f = 0; f < 4; ++f)
        d[f] = *(const half8*)(base + frag_off(fb0 + 16 * f, lrow, lc));
}

template <int MH>
__device__ __forceinline__ void mm16(f32x4 (&acc)[8][4], const half8 (&a)[4],
                                     const half8 (&b)[4]) {
#pragma unroll
    for (int i = 0; i < 4; ++i)
#pragma unroll
        for (int j = 0; j < 4; ++j)
            acc[MH * 4 + i][j] =
                __builtin_amdgcn_mfma_f32_16x16x32_f16(a[i], b[j], acc[MH * 4 + i][j], 0, 0, 0);
}

__device__ __forceinline__ void stage_tile(_Float16* dst, const _Float16* g, int ld,
                                           int ldsoff) {
    // [256][32] f16 tile = 2 gll16 groups of 128 rows (512 thr x 16B each)
    gll16(g, dst + ldsoff);
    gll16(g + (long)128 * ld, dst + 4096 + ldsoff);
}

template <int OUTMODE>
__global__ __launch_bounds__(512, 2) void gemm5p(
    const _Float16* __restrict__ A0, const _Float16* __restrict__ A1,
    const _Float16* __restrict__ B0, const _Float16* __restrict__ B1,
    float* __restrict__ Cf, _Float16* __restrict__ C0, _Float16* __restrict__ C1,
    int lda, int ldb, int ldc, int K,
    long sA, long sB, long sC, float scale, float scale2) {
    __shared__ alignas(16) _Float16 smem[65536];  // 128 KiB: 2 x {A0,B0,A1,B1}

    const int tid = threadIdx.x;
    const int wave = tid >> 6, lane = tid & 63;
    const int wm = (wave >> 2) * 128, wn = (wave & 3) * 64;
    const int lrow = lane & 15, lc = lane >> 4;

    const long zA = (long)blockIdx.z * sA;
    const long zB = (long)blockIdx.z * sB;
    const long zC = (long)blockIdx.z * sC;
    const float sc = (blockIdx.y * 2 < gridDim.y) ? scale : scale2;

    // staging: thread t covers row t>>2 (+128 for 2nd group), phys chunk t&3,
    // fetching logical chunk ((t&3) - f(t>>2)) & 3; f(r+128)==f(r) mod 4.
    const int trow = tid >> 2;
    const int tcol = (((tid & 3) - ((tid >> 3) & 3) - ((tid >> 6) & 3)) & 3) * 8;
    const _Float16* gA0 = A0 + zA + (long)(blockIdx.x * 256 + trow) * lda + tcol;
    const _Float16* gB0 = B0 + zB + (long)(blockIdx.y * 256 + trow) * ldb + tcol;
    const _Float16* gA1 = A1 + zA + (long)(blockIdx.x * 256 + trow) * lda + tcol;
    const _Float16* gB1 = B1 + zB + (long)(blockIdx.y * 256 + trow) * ldb + tcol;

    const int ldsoff = tid * 8;  // halves; *2B = tid*16 bytes

    f32x4 acc[8][4];
#pragma unroll
    for (int i = 0; i < 8; ++i)
#pragma unroll
        for (int j = 0; j < 4; ++j)
#pragma unroll
            for (int r = 0; r < 4; ++r) acc[i][j][r] = 0.f;

    const int nT = K >> 5;

    // prologue: stage tile 0 into buf 0; only A0,B0 must land before P0,
    // so wait with 4 outstanding (A1,B1 forced at end-P1 of step 0).
    {
        _Float16* s = smem;
        stage_tile(s + 0, gA0, lda, ldsoff);
        stage_tile(s + 8192, gB0, ldb, ldsoff);
        stage_tile(s + 16384, gA1, lda, ldsoff);
        stage_tile(s + 24576, gB1, ldb, ldsoff);
        gA0 += 32; gB0 += 32; gA1 += 32; gB1 += 32;
        vmwait4();
        __builtin_amdgcn_s_barrier();
    }

    int buf = 0;
    for (int t = 0; t < nT; ++t) {
        _Float16* scur = smem + buf * 32768;
        _Float16* snx = smem + (buf ^ 1) * 32768;
        const bool pre = (t + 1 < nT);

        half8 a0L[4], a0H[4], a1L[4], a1H[4], b0[4], b1[4];

        // ---- P0: a0L x b0; stage next A0 ----
        ld4(a0L, scur, wm, lrow, lc);
        ld4(b0, scur + 8192, wn, lrow, lc);
        if (pre) { stage_tile(snx + 0, gA0, lda, ldsoff); gA0 += 32; }
        __builtin_amdgcn_s_barrier();
        lgkm0_pin();
        __builtin_amdgcn_s_setprio(1);
        mm16<0>(acc, a0L, b0);
        __builtin_amdgcn_s_setprio(0);
        __builtin_amdgcn_s_barrier();

        // ---- P1: a0H x b0; stage next B0; counted wait for THIS step's A1,B1 ----
        ld4(a0H, scur, wm + 64, lrow, lc);
        if (pre) { stage_tile(snx + 8192, gB0, ldb, ldsoff); gB0 += 32; }
        __builtin_amdgcn_s_barrier();
        lgkm0_pin();
        __builtin_amdgcn_s_setprio(1);
        mm16<1>(acc, a0H, b0);
        __builtin_amdgcn_s_setprio(0);
        if (pre) vmwait4();  // forces A1,B1(t); leaves A0,B0(t+1) in flight
        else vmwait0();      // last iter: drain 4-phase-old A1,B1(t)
        __builtin_amdgcn_s_barrier();

        // ---- P2: a0H x b1; stage next A1+B1 ----
        ld4(b1, scur + 24576, wn, lrow, lc);
        if (pre) {
            stage_tile(snx + 16384, gA1, lda, ldsoff); gA1 += 32;
            stage_tile(snx + 24576, gB1, ldb, ldsoff); gB1 += 32;
        }
        __builtin_amdgcn_s_barrier();
        lgkm0_pin();
        __builtin_amdgcn_s_setprio(1);
        mm16<1>(acc, a0H, b1);
        __builtin_amdgcn_s_setprio(0);
        __builtin_amdgcn_s_barrier();

        // ---- P3: a0L x b1 ----
        ld4(a1L, scur + 16384, wm, lrow, lc);
        __builtin_amdgcn_s_barrier();
        lgkm0_pin();
        __builtin_amdgcn_s_setprio(1);
        mm16<0>(acc, a0L, b1);
        __builtin_amdgcn_s_setprio(0);
        __builtin_amdgcn_s_barrier();

        // ---- P4: a1L x b0, a1H x b0; counted wait for next step's A0,B0 ----
        ld4(a1H, scur + 16384, wm + 64, lrow, lc);
        __builtin_amdgcn_s_barrier();
        lgkm0_pin();
        __builtin_amdgcn_s_setprio(1);
        mm16<0>(acc, a1L, b0);
        mm16<1>(acc, a1H, b0);
        __builtin_amdgcn_s_setprio(0);
        if (pre) vmwait4();  // forces A0,B0(t+1); leaves A1,B1(t+1) in flight
        __builtin_amdgcn_s_barrier();

        buf ^= 1;
    }

    // epilogue: C/D layout col=lane&15, row=(lane>>4)*4+reg
    const int crow0 = blockIdx.x * 256 + wm + lc * 4;
    const int ccol0 = blockIdx.y * 256 + wn + lrow;
#pragma unroll
    for (int mf = 0; mf < 8; ++mf)
#pragma unroll
        for (int nf = 0; nf < 4; ++nf)
#pragma unroll
            for (int r = 0; r < 4; ++r) {
                int row = crow0 + mf * 16 + r;
                long off = zC + (long)row * ldc + (ccol0 + nf * 16);
                float v = acc[mf][nf][r] * sc;
                if (OUTMODE == 0) {
                    Cf[off] = v;
                } else {
                    _Float16 h = (_Float16)v;
                    C0[off] = h;
                    C1[off] = (_Float16)(v - (float)h);
                }
            }
}

// ---------------------------------------------------------------------------
// Fused prep: blocks [0, NSPLIT) do the x fp32 -> f16 hi/lo split (x4 vec);
// blocks [NSPLIT, NSPLIT+3072) transpose+split the three weight matrices.
// ---------------------------------------------------------------------------
__global__ __launch_bounds__(256) void prep_fused(
    const float* __restrict__ x, _Float16* __restrict__ x0, _Float16* __restrict__ x1,
    long n4, int nsplit,
    const float* __restrict__ wq, const float* __restrict__ wk,
    const float* __restrict__ wv,
    _Float16* __restrict__ qk0, _Float16* __restrict__ qk1,
    _Float16* __restrict__ v0, _Float16* __restrict__ v1) {
    __shared__ float t[32][33];
    if ((int)blockIdx.x < nsplit) {
        long i = (long)blockIdx.x * 256 + threadIdx.x;
        if (i >= n4) return;
        float4 v = ((const float4*)x)[i];
        float a[4] = {v.x, v.y, v.z, v.w};
        half4v h, l;
#pragma unroll
        for (int c = 0; c < 4; ++c) {
            h[c] = (_Float16)a[c];
            l[c] = (_Float16)(a[c] - (float)h[c]);
        }
        ((half4v*)x0)[i] = h;
        ((half4v*)x1)[i] = l;
        return;
    }
    const int idx = blockIdx.x - nsplit;
    const int z = idx >> 10;
    const int tile = idx & 1023;
    const float* in = (z == 0) ? wq : (z == 1) ? wk : wv;
    _Float16* o0 = (z == 0) ? qk0 : (z == 1) ? qk0 + 1024 * 1024 : v0;
    _Float16* o1 = (z == 0) ? qk1 : (z == 1) ? qk1 + 1024 * 1024 : v1;

    const int c0 = (tile & 31) * 32, r0 = (tile >> 5) * 32;
    const int tx = threadIdx.x & 31, ty = threadIdx.x >> 5;
#pragma unroll
    for (int i = 0; i < 32; i += 8)
        t[ty + i][tx] = in[(long)(r0 + ty + i) * 1024 + c0 + tx];
    __syncthreads();
#pragma unroll
    for (int i = 0; i < 32; i += 8) {
        float v = t[tx][ty + i];
        _Float16 h = (_Float16)v;
        long o = (long)(c0 + ty + i) * 1024 + r0 + tx;
        o0[o] = h;
        o1[o] = (_Float16)(v - (float)h);
    }
}

// ---------------------------------------------------------------------------
// row softmax: S fp32 [8192][2048] -> P f16, one block per row (vectorized)
// ---------------------------------------------------------------------------
__global__ __launch_bounds__(256) void softmax_rows(const float* __restrict__ S,
                                                    _Float16* __restrict__ P) {
    const int n = 2048;
    const long base = (long)blockIdx.x * n;
    const float4* row4 = (const float4*)(S + base);
    const int tid = threadIdx.x;
    const int wave = tid >> 6;

    float4 v0 = row4[tid * 2];
    float4 v1 = row4[tid * 2 + 1];
    float v[8] = {v0.x, v0.y, v0.z, v0.w, v1.x, v1.y, v1.z, v1.w};
    float lm = -3.4e38f;
#pragma unroll
    for (int t = 0; t < 8; ++t) lm = fmaxf(lm, v[t]);
#pragma unroll
    for (int o = 32; o > 0; o >>= 1) lm = fmaxf(lm, __shfl_xor(lm, o));
    __shared__ float redm[4];
    __shared__ float reds[4];
    if ((tid & 63) == 0) redm[wave] = lm;
    __syncthreads();
    lm = fmaxf(fmaxf(redm[0], redm[1]), fmaxf(redm[2], redm[3]));

    float e[8];
    float ls = 0.f;
#pragma unroll
    for (int t = 0; t < 8; ++t) {
        e[t] = __expf(v[t] - lm);
        ls += e[t];
    }
#pragma unroll
    for (int o = 32; o > 0; o >>= 1) ls += __shfl_xor(ls, o);
    if ((tid & 63) == 0) reds[wave] = ls;
    __syncthreads();
    ls = reds[0] + reds[1] + reds[2] + reds[3];
    const float inv = 1.f / ls;
    half8 p;
#pragma unroll
    for (int t = 0; t < 8; ++t) p[t] = (_Float16)(e[t] * inv);
    ((half8*)(P + base))[tid] = p;
}

// ---------------------------------------------------------------------------
extern "C" void kernel_launch(void* const* d_in, const int* in_sizes, int n_in,
                              void* d_out, int out_size, void* d_ws, size_t ws_size,
                              hipStream_t stream) {
    (void)in_sizes; (void)n_in; (void)out_size; (void)ws_size;
    const float* x = (const float*)d_in[0];
    const float* wq = (const float*)d_in[1];
    const float* wk = (const float*)d_in[2];
    const float* wv = (const float*)d_in[3];
    float* out = (float*)d_out;
    char* ws = (char*)d_ws;

    const long MB = 1l << 20;
    // ws layout (188 MB):
    _Float16* Wqk0 = (_Float16*)(ws + 0 * MB);   // [2048][1024] 4 MB
    _Float16* Wqk1 = (_Float16*)(ws + 4 * MB);   // 4 MB
    _Float16* Wv0  = (_Float16*)(ws + 8 * MB);   // 2 MB
    _Float16* Wv1  = (_Float16*)(ws + 10 * MB);  // 2 MB (unused by NPROD=1 path)
    _Float16* x0   = (_Float16*)(ws + 12 * MB);  // 16 MB
    _Float16* x1   = (_Float16*)(ws + 28 * MB);  // 16 MB
    _Float16* P    = (_Float16*)(ws + 12 * MB);  // 32 MB, reuses dead x0/x1
    _Float16* QK0  = (_Float16*)(ws + 44 * MB);  // [8192][2048] 32 MB
    _Float16* QK1  = (_Float16*)(ws + 76 * MB);  // 32 MB
    _Float16* Vt   = (_Float16*)(ws + 108 * MB); // [1024][8192] 16 MB
    float*    S    = (float*)(ws + 124 * MB);    // 64 MB

    const int B = 4, SEQ = 2048, D = 1024;
    const long M = (long)B * SEQ;  // 8192
    const long ssq = (long)SEQ * SEQ;  // per-batch S stride
    const int nsplit = (int)((M * D / 4 + 255) / 256);  // 8192

    // 1) fused prep: x split + weight transpose/split (one dispatch)
    prep_fused<<<dim3(nsplit + 3072), dim3(256), 0, stream>>>(
        x, x0, x1, M * D / 4, nsplit, wq, wk, wv, Wqk0, Wqk1, Wv0, Wv1);

    // 2) fused Q|K projection (5-phase 256^2, counted vmcnt): QK[m][n], split out
    gemm5p<1><<<dim3(32, 8, 1), dim3(512), 0, stream>>>(
        x0, x1, Wqk0, Wqk1, nullptr, QK0, QK1, D, D, 2 * D, D,
        0, 0, 0, 0.03125f, 1.0f);

    // 3) V^T directly: Vt[e][m] = sum_d Wv^T[e][d] * x[m][d]  (NT, A=Wv^T, B=x)
    gemm_nt<1, 2><<<dim3(8, 64, 1), dim3(256), 0, stream>>>(
        Wv0, nullptr, x0, nullptr, nullptr, Vt, nullptr, D, D, (int)M, D,
        0, 0, 0, 1.0f, 1.0f);

    // 4) S = Qs @ K^T (5-phase 256^2, counted vmcnt, fp32 out)
    gemm5p<0><<<dim3(8, 8, B), dim3(512), 0, stream>>>(
        QK0, QK1, QK0 + D, QK1 + D, S, nullptr, nullptr, 2 * D, 2 * D, SEQ, D,
        (long)SEQ * 2 * D, (long)SEQ * 2 * D, ssq, 1.0f, 1.0f);

    // 5) P = rowsoftmax(S) as f16
    softmax_rows<<<dim3(B * SEQ), dim3(256), 0, stream>>>(S, P);

    // 6) out = P @ V = P @ (Vt batch-view)^T ; Vt batch b = cols b*2048..
    gemm_nt<1, 0><<<dim3(16, 8, B), dim3(256), 0, stream>>>(
        P, nullptr, Vt, nullptr, out, nullptr, nullptr, SEQ, (int)M, D, SEQ,
        ssq, (long)SEQ, (long)SEQ * D, 1.0f, 1.0f);
}

// Round 5
// 352.720 us; speedup vs baseline: 1.1196x; 1.0129x over previous
//
#include <hip/hip_runtime.h>
#include <hip/hip_bf16.h>

// HybridSelfAttention: out = softmax((xWq)(xWk)^T / sqrt(d)) (xWv)
// B=4, S=2048, D=1024, fp32 in/out.
//
// Precision: f16 hi/lo split + 3-product MFMA for xWq, xWk, QK^T (softmax is
// near-one-hot; S must be ~fp32-accurate). Plain f16 MFMA for V^T and PV.
//
// R1: LDS chunk swizzle -> bank conflicts 8.4M -> 0.
// R2: dispatch fusion (QK proj fused, V^T direct GEMM, weight prep merged).
// R3: MFMA 32x32x16.
// R5: swizzle fix f(r)=((r>>1)+(r>>4))&3 -> conflicts 0.
// R6/R7: register-staging transport -> compiler spilled -> dead end.
// R8: double-buffered LDS, one barrier per K-iter -> 888 TF effective.
// R9: 256^2 8-wave 3-phase port -> 977 TF (MfmaUtil 44): coarse phases
//   serialize LDS drain against MFMA windows.
// R10: m201 granularity (16x16x32, 5 phases, 16-MFMA clusters) -> 98 us,
//   MfmaUtil 45.6.
// R11/R12: T4 counted vmcnt (never 0 in main loop) -> 100.5 us, MfmaUtil 44.
//   UNCHANGED vs drain-0 => load-drain was never the stall (BK=32 makes all
//   drained loads ~2000 cyc old; vmcnt(0) was already free).
// R13: barrier audit. Per K-step the 5-phase loop had 10 s_barriers; only 2
//   are correctness-bearing:
//     end-P1 {vmcnt;barrier}: publishes A1,B1(t) gll16 writes (per-wave vmcnt
//       retire -> block-visible) before P2/P3/P4 read them.
//     end-P4 {vmcnt;barrier}: publishes A0,B0(t+1) AND WAR-protects scur(t)
//       (each wave's reads are lgkm0-complete before arrival; after release
//       the t+1 stages may overwrite).
//   The other 8 are scheduling-only lockstep: they charge 8-wave skew 10x per
//   step and prevent the 2 waves/SIMD from overlapping ds_read windows with
//   MFMA clusters. Removed. Per-phase lgkmcnt(0)+sched_barrier(0) retained
//   (own-wave read ordering + rule-18 compiler fence). vmcnt ledger is
//   per-wave/in-order -> unchanged by barrier count.

typedef _Float16 half8 __attribute__((ext_vector_type(8)));
typedef _Float16 half4v __attribute__((ext_vector_type(4)));
typedef float f32x16 __attribute__((ext_vector_type(16)));
typedef float f32x4 __attribute__((ext_vector_type(4)));

#define GLOBAL_AS __attribute__((address_space(1)))
#define LDS_AS __attribute__((address_space(3)))

__device__ __forceinline__ void gll16(const _Float16* g, _Float16* l) {
    // async global->LDS DMA, 16B per lane; LDS dest is wave-uniform base + lane*16
    __builtin_amdgcn_global_load_lds((GLOBAL_AS const void*)g, (LDS_AS void*)l, 16, 0, 0);
}

__device__ __forceinline__ void lgkm0_pin() {
    // rule 18: sched_barrier(0) right after an inline-asm lgkmcnt wait, else
    // hipcc can hoist register-only MFMA above the wait.
    asm volatile("s_waitcnt lgkmcnt(0)" ::: "memory");
    __builtin_amdgcn_sched_barrier(0);
}

__device__ __forceinline__ void vmwait0() {
    asm volatile("s_waitcnt vmcnt(0)" ::: "memory");
}

__device__ __forceinline__ void vmwait4() {
    asm volatile("s_waitcnt vmcnt(4)" ::: "memory");
}

// ---------------------------------------------------------------------------
// OLD 128x128 kernel (R8 structure) -- kept for the NPROD=1 ops (V^T, PV),
// whose grids would under-fill the chip at 256^2 tiles.
// ---------------------------------------------------------------------------
template <int NPROD, int OUTMODE>
__global__ __launch_bounds__(256) void gemm_nt(
    const _Float16* __restrict__ A0, const _Float16* __restrict__ A1,
    const _Float16* __restrict__ B0, const _Float16* __restrict__ B1,
    float* __restrict__ Cf, _Float16* __restrict__ C0, _Float16* __restrict__ C1,
    int lda, int ldb, int ldc, int K,
    long sA, long sB, long sC, float scale, float scale2) {
    constexpr int NTILES = (NPROD == 3) ? 4 : 2;
    constexpr int BUFH = NTILES * 4096;  // halves per buffer set
    __shared__ alignas(16) _Float16 smem[2 * BUFH];  // double-buffered tile sets

    const int tid = threadIdx.x;
    const int wave = tid >> 6, lane = tid & 63;
    const int wm = (wave >> 1) * 64, wn = (wave & 1) * 64;
    const int q2 = lane >> 5, r32 = lane & 31;

    const long zA = (long)blockIdx.z * sA;
    const long zB = (long)blockIdx.z * sB;
    const long zC = (long)blockIdx.z * sC;

    const float sc = (blockIdx.y * 2 < gridDim.y) ? scale : scale2;

    const int trow = tid >> 2;
    const int tcol = (((tid & 3) - ((tid >> 3) & 3) - ((tid >> 6) & 3)) & 3) * 8;
    const _Float16* gA0 = A0 + zA + (long)(blockIdx.x * 128 + trow) * lda + tcol;
    const _Float16* gB0 = B0 + zB + (long)(blockIdx.y * 128 + trow) * ldb + tcol;
    const _Float16* gA1 = (NPROD == 3) ? (A1 + zA + (long)(blockIdx.x * 128 + trow) * lda + tcol) : nullptr;
    const _Float16* gB1 = (NPROD == 3) ? (B1 + zB + (long)(blockIdx.y * 128 + trow) * ldb + tcol) : nullptr;

    f32x16 acc[2][2];
#pragma unroll
    for (int i = 0; i < 2; ++i)
#pragma unroll
        for (int j = 0; j < 2; ++j)
#pragma unroll
            for (int r = 0; r < 16; ++r) acc[i][j][r] = 0.f;

    const int ldsoff = tid * 8;
    const int fbase = q2 + (r32 >> 1) + (r32 >> 4);

    {
        _Float16* s = smem;
        gll16(gA0, s + ldsoff);
        gll16(gA0 + 64 * lda, s + ldsoff + 2048);
        gll16(gB0, s + 4096 + ldsoff);
        gll16(gB0 + 64 * ldb, s + 4096 + ldsoff + 2048);
        if (NPROD == 3) {
            gll16(gA1, s + 8192 + ldsoff);
            gll16(gA1 + 64 * lda, s + 8192 + ldsoff + 2048);
            gll16(gB1, s + 12288 + ldsoff);
            gll16(gB1 + 64 * ldb, s + 12288 + ldsoff + 2048);
        }
        gA0 += 32; gB0 += 32;
        if (NPROD == 3) { gA1 += 32; gB1 += 32; }
    }

    int buf = 0;
    for (int k0 = 0; k0 < K; k0 += 32) {
        __syncthreads();

        if (k0 + 32 < K) {
            _Float16* s = smem + (buf ^ 1) * BUFH;
            gll16(gA0, s + ldsoff);
            gll16(gA0 + 64 * lda, s + ldsoff + 2048);
            gll16(gB0, s + 4096 + ldsoff);
            gll16(gB0 + 64 * ldb, s + 4096 + ldsoff + 2048);
            if (NPROD == 3) {
                gll16(gA1, s + 8192 + ldsoff);
                gll16(gA1 + 64 * lda, s + 8192 + ldsoff + 2048);
                gll16(gB1, s + 12288 + ldsoff);
                gll16(gB1 + 64 * ldb, s + 12288 + ldsoff + 2048);
            }
            gA0 += 32; gB0 += 32;
            if (NPROD == 3) { gA1 += 32; gB1 += 32; }
        }

        _Float16* sA0 = smem + buf * BUFH;
        _Float16* sB0 = sA0 + 4096;
        _Float16* sA1 = (NPROD == 3) ? sA0 + 8192 : sA0;
        _Float16* sB1 = (NPROD == 3) ? sA0 + 12288 : sA0;
#pragma unroll
        for (int h = 0; h < 2; ++h) {
            half8 a0[2], b0[2], a1[2], b1[2];
#pragma unroll
            for (int i = 0; i < 2; ++i) {
                const int pp = ((fbase + 2 * i + 2 * h) & 3) * 8;
                a0[i] = *(const half8*)(sA0 + (wm + i * 32 + r32) * 32 + pp);
                b0[i] = *(const half8*)(sB0 + (wn + i * 32 + r32) * 32 + pp);
                if (NPROD == 3) {
                    a1[i] = *(const half8*)(sA1 + (wm + i * 32 + r32) * 32 + pp);
                    b1[i] = *(const half8*)(sB1 + (wn + i * 32 + r32) * 32 + pp);
                }
            }
#pragma unroll
            for (int i = 0; i < 2; ++i)
#pragma unroll
                for (int j = 0; j < 2; ++j) {
                    acc[i][j] = __builtin_amdgcn_mfma_f32_32x32x16_f16(a0[i], b0[j], acc[i][j], 0, 0, 0);
                    if (NPROD == 3) {
                        acc[i][j] = __builtin_amdgcn_mfma_f32_32x32x16_f16(a0[i], b1[j], acc[i][j], 0, 0, 0);
                        acc[i][j] = __builtin_amdgcn_mfma_f32_32x32x16_f16(a1[i], b0[j], acc[i][j], 0, 0, 0);
                    }
                }
        }
        buf ^= 1;
    }

    const int crow0 = blockIdx.x * 128 + wm + 4 * q2;
    const int ccol0 = blockIdx.y * 128 + wn + r32;
#pragma unroll
    for (int i = 0; i < 2; ++i)
#pragma unroll
        for (int j = 0; j < 2; ++j)
#pragma unroll
            for (int r = 0; r < 16; ++r) {
                int row = crow0 + i * 32 + (r & 3) + 8 * (r >> 2);
                long off = zC + (long)row * ldc + (ccol0 + j * 32);
                float v = acc[i][j][r] * sc;
                if (OUTMODE == 0) {
                    Cf[off] = v;
                } else if (OUTMODE == 2) {
                    C0[off] = (_Float16)v;
                } else {
                    _Float16 h = (_Float16)v;
                    C0[off] = h;
                    C1[off] = (_Float16)(v - (float)h);
                }
            }
}

// ---------------------------------------------------------------------------
// 256x256-tile, 8-wave, 5-phase NT GEMM, 2 barriers/K-step (R13).
// C[M,N] = (A0+A1)(B0+B1)^T ~= A0B0 + A0B1 + A1B0.
// 512 thr = 8 waves (2 M x 4 N), per-wave 128x64 output, acc = 32 x f32x4.
// MFMA 16x16x32_f16. BK=32; LDS: 2 bufs x {A0,B0,A1,B1} x [256][32] = 128 KiB.
// Per K-step:
//   P0: ld a0L,b0; stage A0(t+1); lgkm0; MFMA
//   P1: ld a0H;    stage B0(t+1); lgkm0; MFMA; vmcnt(4); BARRIER
//        (forces A1,B1(t) -- issued P2 of t-1 -- publishes for P2..P4)
//   P2: ld b1;     stage A1,B1(t+1); lgkm0; MFMA
//   P3: ld a1L;    lgkm0; MFMA
//   P4: ld a1H;    lgkm0; MFMA x2; vmcnt(4); BARRIER
//        (forces A0,B0(t+1); WAR-protects scur(t): every wave's reads are
//         lgkm0-complete before it arrives)
// vmcnt ledger (per-wave, in-order): prologue 8 -> vmwait4 leaves A1,B1(0).
// Steady: P0 +2, P1 +2 -> 8; end-P1 vmwait4 forces oldest 4 = A1,B1(t).
// P2 +4 -> 8; end-P4 vmwait4 forces oldest 4 = A0,B0(t+1). Last iter
// (pre=false): end-P1 vmwait0 drains the leftover 4; no end-P4 sync needed.
// Swizzle: phys chunk p of row r = (c + f(r))&3, f(r)=((r>>1)+(r>>4))&3;
// 16-row fragment at base FB: f == (FB>>4 + ((lane&15)>>1)) & 3, conflict-free.
// ---------------------------------------------------------------------------
__device__ __forceinline__ int frag_off(int fb, int lrow, int lc) {
    // offset in halves within a [256][32] tile for fragment base row fb
    return (fb + lrow) * 32 + ((((fb >> 4) + lc + (lrow >> 1)) & 3) << 3);
}

__device__ __forceinline__ void ld4(half8 (&d)[4], const _Float16* base, int fb0,
                                    int lrow, int lc) {
#pragma unroll
    for (int f = 0; f < 4; ++f)
        d[f] = *(const half8*)(base + frag_off(fb0 + 16 * f, lrow, lc));
}

template <int MH>
__device__ __forceinline__ void mm16(f32x4 (&acc)[8][4], const half8 (&a)[4],
                                     const half8 (&b)[4]) {
#pragma unroll
    for (int i = 0; i < 4; ++i)
#pragma unroll
        for (int j = 0; j < 4; ++j)
            acc[MH * 4 + i][j] =
                __builtin_amdgcn_mfma_f32_16x16x32_f16(a[i], b[j], acc[MH * 4 + i][j], 0, 0, 0);
}

__device__ __forceinline__ void stage_tile(_Float16* dst, const _Float16* g, int ld,
                                           int ldsoff) {
    // [256][32] f16 tile = 2 gll16 groups of 128 rows (512 thr x 16B each)
    gll16(g, dst + ldsoff);
    gll16(g + (long)128 * ld, dst + 4096 + ldsoff);
}

template <int OUTMODE>
__global__ __launch_bounds__(512, 2) void gemm5p(
    const _Float16* __restrict__ A0, const _Float16* __restrict__ A1,
    const _Float16* __restrict__ B0, const _Float16* __restrict__ B1,
    float* __restrict__ Cf, _Float16* __restrict__ C0, _Float16* __restrict__ C1,
    int lda, int ldb, int ldc, int K,
    long sA, long sB, long sC, float scale, float scale2) {
    __shared__ alignas(16) _Float16 smem[65536];  // 128 KiB: 2 x {A0,B0,A1,B1}

    const int tid = threadIdx.x;
    const int wave = tid >> 6, lane = tid & 63;
    const int wm = (wave >> 2) * 128, wn = (wave & 3) * 64;
    const int lrow = lane & 15, lc = lane >> 4;

    const long zA = (long)blockIdx.z * sA;
    const long zB = (long)blockIdx.z * sB;
    const long zC = (long)blockIdx.z * sC;
    const float sc = (blockIdx.y * 2 < gridDim.y) ? scale : scale2;

    // staging: thread t covers row t>>2 (+128 for 2nd group), phys chunk t&3,
    // fetching logical chunk ((t&3) - f(t>>2)) & 3; f(r+128)==f(r) mod 4.
    const int trow = tid >> 2;
    const int tcol = (((tid & 3) - ((tid >> 3) & 3) - ((tid >> 6) & 3)) & 3) * 8;
    const _Float16* gA0 = A0 + zA + (long)(blockIdx.x * 256 + trow) * lda + tcol;
    const _Float16* gB0 = B0 + zB + (long)(blockIdx.y * 256 + trow) * ldb + tcol;
    const _Float16* gA1 = A1 + zA + (long)(blockIdx.x * 256 + trow) * lda + tcol;
    const _Float16* gB1 = B1 + zB + (long)(blockIdx.y * 256 + trow) * ldb + tcol;

    const int ldsoff = tid * 8;  // halves; *2B = tid*16 bytes

    f32x4 acc[8][4];
#pragma unroll
    for (int i = 0; i < 8; ++i)
#pragma unroll
        for (int j = 0; j < 4; ++j)
#pragma unroll
            for (int r = 0; r < 4; ++r) acc[i][j][r] = 0.f;

    const int nT = K >> 5;

    // prologue: stage tile 0 into buf 0; only A0,B0 must land before P0,
    // so wait with 4 outstanding (A1,B1 forced at end-P1 of step 0).
    {
        _Float16* s = smem;
        stage_tile(s + 0, gA0, lda, ldsoff);
        stage_tile(s + 8192, gB0, ldb, ldsoff);
        stage_tile(s + 16384, gA1, lda, ldsoff);
        stage_tile(s + 24576, gB1, ldb, ldsoff);
        gA0 += 32; gB0 += 32; gA1 += 32; gB1 += 32;
        vmwait4();
        __builtin_amdgcn_s_barrier();
    }

    int buf = 0;
    for (int t = 0; t < nT; ++t) {
        _Float16* scur = smem + buf * 32768;
        _Float16* snx = smem + (buf ^ 1) * 32768;
        const bool pre = (t + 1 < nT);

        half8 a0L[4], a0H[4], a1L[4], a1H[4], b0[4], b1[4];

        // ---- P0: a0L x b0; stage next A0 ----
        ld4(a0L, scur, wm, lrow, lc);
        ld4(b0, scur + 8192, wn, lrow, lc);
        if (pre) { stage_tile(snx + 0, gA0, lda, ldsoff); gA0 += 32; }
        lgkm0_pin();
        __builtin_amdgcn_s_setprio(1);
        mm16<0>(acc, a0L, b0);
        __builtin_amdgcn_s_setprio(0);

        // ---- P1: a0H x b0; stage next B0; SYNC #1 ----
        ld4(a0H, scur, wm + 64, lrow, lc);
        if (pre) { stage_tile(snx + 8192, gB0, ldb, ldsoff); gB0 += 32; }
        lgkm0_pin();
        __builtin_amdgcn_s_setprio(1);
        mm16<1>(acc, a0H, b0);
        __builtin_amdgcn_s_setprio(0);
        if (pre) vmwait4();  // forces A1,B1(t); leaves A0,B0(t+1) in flight
        else vmwait0();      // last iter: drain 4-phase-old A1,B1(t)
        __builtin_amdgcn_s_barrier();  // publish A1,B1(t) to all waves

        // ---- P2: a0H x b1; stage next A1+B1 ----
        ld4(b1, scur + 24576, wn, lrow, lc);
        if (pre) {
            stage_tile(snx + 16384, gA1, lda, ldsoff); gA1 += 32;
            stage_tile(snx + 24576, gB1, ldb, ldsoff); gB1 += 32;
        }
        lgkm0_pin();
        __builtin_amdgcn_s_setprio(1);
        mm16<1>(acc, a0H, b1);
        __builtin_amdgcn_s_setprio(0);

        // ---- P3: a0L x b1 ----
        ld4(a1L, scur + 16384, wm, lrow, lc);
        lgkm0_pin();
        __builtin_amdgcn_s_setprio(1);
        mm16<0>(acc, a0L, b1);
        __builtin_amdgcn_s_setprio(0);

        // ---- P4: a1L x b0, a1H x b0; SYNC #2 ----
        ld4(a1H, scur + 16384, wm + 64, lrow, lc);
        lgkm0_pin();
        __builtin_amdgcn_s_setprio(1);
        mm16<0>(acc, a1L, b0);
        mm16<1>(acc, a1H, b0);
        __builtin_amdgcn_s_setprio(0);
        if (pre) {
            vmwait4();  // forces A0,B0(t+1); leaves A1,B1(t+1) in flight
            __builtin_amdgcn_s_barrier();  // publish + WAR-protect scur(t)
        }

        buf ^= 1;
    }

    // epilogue: C/D layout col=lane&15, row=(lane>>4)*4+reg
    const int crow0 = blockIdx.x * 256 + wm + lc * 4;
    const int ccol0 = blockIdx.y * 256 + wn + lrow;
#pragma unroll
    for (int mf = 0; mf < 8; ++mf)
#pragma unroll
        for (int nf = 0; nf < 4; ++nf)
#pragma unroll
            for (int r = 0; r < 4; ++r) {
                int row = crow0 + mf * 16 + r;
                long off = zC + (long)row * ldc + (ccol0 + nf * 16);
                float v = acc[mf][nf][r] * sc;
                if (OUTMODE == 0) {
                    Cf[off] = v;
                } else {
                    _Float16 h = (_Float16)v;
                    C0[off] = h;
                    C1[off] = (_Float16)(v - (float)h);
                }
            }
}

// ---------------------------------------------------------------------------
// Fused prep: blocks [0, NSPLIT) do the x fp32 -> f16 hi/lo split (x4 vec);
// blocks [NSPLIT, NSPLIT+3072) transpose+split the three weight matrices.
// ---------------------------------------------------------------------------
__global__ __launch_bounds__(256) void prep_fused(
    const float* __restrict__ x, _Float16* __restrict__ x0, _Float16* __restrict__ x1,
    long n4, int nsplit,
    const float* __restrict__ wq, const float* __restrict__ wk,
    const float* __restrict__ wv,
    _Float16* __restrict__ qk0, _Float16* __restrict__ qk1,
    _Float16* __restrict__ v0, _Float16* __restrict__ v1) {
    __shared__ float t[32][33];
    if ((int)blockIdx.x < nsplit) {
        long i = (long)blockIdx.x * 256 + threadIdx.x;
        if (i >= n4) return;
        float4 v = ((const float4*)x)[i];
        float a[4] = {v.x, v.y, v.z, v.w};
        half4v h, l;
#pragma unroll
        for (int c = 0; c < 4; ++c) {
            h[c] = (_Float16)a[c];
            l[c] = (_Float16)(a[c] - (float)h[c]);
        }
        ((half4v*)x0)[i] = h;
        ((half4v*)x1)[i] = l;
        return;
    }
    const int idx = blockIdx.x - nsplit;
    const int z = idx >> 10;
    const int tile = idx & 1023;
    const float* in = (z == 0) ? wq : (z == 1) ? wk : wv;
    _Float16* o0 = (z == 0) ? qk0 : (z == 1) ? qk0 + 1024 * 1024 : v0;
    _Float16* o1 = (z == 0) ? qk1 : (z == 1) ? qk1 + 1024 * 1024 : v1;

    const int c0 = (tile & 31) * 32, r0 = (tile >> 5) * 32;
    const int tx = threadIdx.x & 31, ty = threadIdx.x >> 5;
#pragma unroll
    for (int i = 0; i < 32; i += 8)
        t[ty + i][tx] = in[(long)(r0 + ty + i) * 1024 + c0 + tx];
    __syncthreads();
#pragma unroll
    for (int i = 0; i < 32; i += 8) {
        float v = t[tx][ty + i];
        _Float16 h = (_Float16)v;
        long o = (long)(c0 + ty + i) * 1024 + r0 + tx;
        o0[o] = h;
        o1[o] = (_Float16)(v - (float)h);
    }
}

// ---------------------------------------------------------------------------
// row softmax: S fp32 [8192][2048] -> P f16, one block per row (vectorized)
// ---------------------------------------------------------------------------
__global__ __launch_bounds__(256) void softmax_rows(const float* __restrict__ S,
                                                    _Float16* __restrict__ P) {
    const int n = 2048;
    const long base = (long)blockIdx.x * n;
    const float4* row4 = (const float4*)(S + base);
    const int tid = threadIdx.x;
    const int wave = tid >> 6;

    float4 v0 = row4[tid * 2];
    float4 v1 = row4[tid * 2 + 1];
    float v[8] = {v0.x, v0.y, v0.z, v0.w, v1.x, v1.y, v1.z, v1.w};
    float lm = -3.4e38f;
#pragma unroll
    for (int t = 0; t < 8; ++t) lm = fmaxf(lm, v[t]);
#pragma unroll
    for (int o = 32; o > 0; o >>= 1) lm = fmaxf(lm, __shfl_xor(lm, o));
    __shared__ float redm[4];
    __shared__ float reds[4];
    if ((tid & 63) == 0) redm[wave] = lm;
    __syncthreads();
    lm = fmaxf(fmaxf(redm[0], redm[1]), fmaxf(redm[2], redm[3]));

    float e[8];
    float ls = 0.f;
#pragma unroll
    for (int t = 0; t < 8; ++t) {
        e[t] = __expf(v[t] - lm);
        ls += e[t];
    }
#pragma unroll
    for (int o = 32; o > 0; o >>= 1) ls += __shfl_xor(ls, o);
    if ((tid & 63) == 0) reds[wave] = ls;
    __syncthreads();
    ls = reds[0] + reds[1] + reds[2] + reds[3];
    const float inv = 1.f / ls;
    half8 p;
#pragma unroll
    for (int t = 0; t < 8; ++t) p[t] = (_Float16)(e[t] * inv);
    ((half8*)(P + base))[tid] = p;
}

// ---------------------------------------------------------------------------
extern "C" void kernel_launch(void* const* d_in, const int* in_sizes, int n_in,
                              void* d_out, int out_size, void* d_ws, size_t ws_size,
                              hipStream_t stream) {
    (void)in_sizes; (void)n_in; (void)out_size; (void)ws_size;
    const float* x = (const float*)d_in[0];
    const float* wq = (const float*)d_in[1];
    const float* wk = (const float*)d_in[2];
    const float* wv = (const float*)d_in[3];
    float* out = (float*)d_out;
    char* ws = (char*)d_ws;

    const long MB = 1l << 20;
    // ws layout (188 MB):
    _Float16* Wqk0 = (_Float16*)(ws + 0 * MB);   // [2048][1024] 4 MB
    _Float16* Wqk1 = (_Float16*)(ws + 4 * MB);   // 4 MB
    _Float16* Wv0  = (_Float16*)(ws + 8 * MB);   // 2 MB
    _Float16* Wv1  = (_Float16*)(ws + 10 * MB);  // 2 MB (unused by NPROD=1 path)
    _Float16* x0   = (_Float16*)(ws + 12 * MB);  // 16 MB
    _Float16* x1   = (_Float16*)(ws + 28 * MB);  // 16 MB
    _Float16* P    = (_Float16*)(ws + 12 * MB);  // 32 MB, reuses dead x0/x1
    _Float16* QK0  = (_Float16*)(ws + 44 * MB);  // [8192][2048] 32 MB
    _Float16* QK1  = (_Float16*)(ws + 76 * MB);  // 32 MB
    _Float16* Vt   = (_Float16*)(ws + 108 * MB); // [1024][8192] 16 MB
    float*    S    = (float*)(ws + 124 * MB);    // 64 MB

    const int B = 4, SEQ = 2048, D = 1024;
    const long M = (long)B * SEQ;  // 8192
    const long ssq = (long)SEQ * SEQ;  // per-batch S stride
    const int nsplit = (int)((M * D / 4 + 255) / 256);  // 8192

    // 1) fused prep: x split + weight transpose/split (one dispatch)
    prep_fused<<<dim3(nsplit + 3072), dim3(256), 0, stream>>>(
        x, x0, x1, M * D / 4, nsplit, wq, wk, wv, Wqk0, Wqk1, Wv0, Wv1);

    // 2) fused Q|K projection (5-phase 256^2, 2-barrier): QK[m][n], split out
    gemm5p<1><<<dim3(32, 8, 1), dim3(512), 0, stream>>>(
        x0, x1, Wqk0, Wqk1, nullptr, QK0, QK1, D, D, 2 * D, D,
        0, 0, 0, 0.03125f, 1.0f);

    // 3) V^T directly: Vt[e][m] = sum_d Wv^T[e][d] * x[m][d]  (NT, A=Wv^T, B=x)
    gemm_nt<1, 2><<<dim3(8, 64, 1), dim3(256), 0, stream>>>(
        Wv0, nullptr, x0, nullptr, nullptr, Vt, nullptr, D, D, (int)M, D,
        0, 0, 0, 1.0f, 1.0f);

    // 4) S = Qs @ K^T (5-phase 256^2, 2-barrier, fp32 out)
    gemm5p<0><<<dim3(8, 8, B), dim3(512), 0, stream>>>(
        QK0, QK1, QK0 + D, QK1 + D, S, nullptr, nullptr, 2 * D, 2 * D, SEQ, D,
        (long)SEQ * 2 * D, (long)SEQ * 2 * D, ssq, 1.0f, 1.0f);

    // 5) P = rowsoftmax(S) as f16
    softmax_rows<<<dim3(B * SEQ), dim3(256), 0, stream>>>(S, P);

    // 6) out = P @ V = P @ (Vt batch-view)^T ; Vt batch b = cols b*2048..
    gemm_nt<1, 0><<<dim3(16, 8, B), dim3(256), 0, stream>>>(
        P, nullptr, Vt, nullptr, out, nullptr, nullptr, SEQ, (int)M, D, SEQ,
        ssq, (long)SEQ, (long)SEQ * D, 1.0f, 1.0f);
}